// Round 1
// baseline (522.078 us; speedup 1.0000x reference)
//
#include <hip/hip_runtime.h>

// Flow_49160195670664: Dopri5 fixed-step integration of dx/dt = A x + B u(t),
// T=32768, N=256, NI=NO=32, dt=1, Hermite-interpolated stage inputs.
// Linear system => x_{n+1} = R x_n + v_n with constant R; 2-level blocked
// parallel scan (32 x 32 x 32). Sequential-chain parts run on MFMA with
// bf16 hi/lo split (x*R ~ xh*Rh + xl*Rh + xh*Rl, fp32 accumulate).

#define TPTS 32768

typedef __attribute__((ext_vector_type(8))) short short8;
typedef __attribute__((ext_vector_type(4))) float float4v;
typedef unsigned short ushort_t;

__device__ __forceinline__ ushort_t bf16_hi(float f) {
  unsigned u = __builtin_bit_cast(unsigned, f);
  unsigned r = (u + 0x7FFFu + ((u >> 16) & 1u)) >> 16;
  return (ushort_t)r;
}
__device__ __forceinline__ float bf16_f(ushort_t h) {
  unsigned u = ((unsigned)h) << 16;
  return __builtin_bit_cast(float, u);
}

// ---------------------------------------------------------------------------
// MFMA chain kernel v2. 512 thr = 8 waves; wave w owns output cols [32w,32w+32)
// as 2 N-tiles of mfma_f32_16x16x32_bf16; 16 chains = MFMA M-dim.
// R^T B-frags live in VGPRs, residency FORCED by per-value "+v" asm pins inside
// the loop (a rw-operand makes reload/remat illegal — the r2-r6 lesson; plain
// memory clobbers don't stop rematerialization, VGPR_Count was 88 not ~190).
// 6 independent accumulators cut dependent-MFMA depth 24 -> 8.
// V-drive is per-lane register-prefetched one step ahead (no vbuf LDS/barrier).
// MODE 2 stores go through a 5-slot LDS ring, flushed 4 rows per 4 steps just
// after a barrier so the global-store drain overlaps the next step's MFMAs.
// MODE 0: power  (32 steps, x0 = I cols; Out=R^32 row-major fp32 + h/l split)
// MODE 1: reduce (31 steps, x0 = V row0, drive rows 1..31; Out[chain] = final x)
// MODE 2: expand (31 steps, x0 = X0, drive rows 0..30; Out rows chain*32+j)
template <int MODE>
__global__ __launch_bounds__(512, 2) void chain_mfma(const ushort_t* Mh, const ushort_t* Ml,
                                                     const float* X0, const float* V,
                                                     float* Out, ushort_t* OutH, ushort_t* OutL) {
  constexpr int STEPS = (MODE == 0) ? 32 : 31;
  constexpr int HSLOTS = (MODE == 2) ? 5 : 1;
  int blk = blockIdx.x, t = threadIdx.x;
  int w = t >> 6, l = t & 63;
  int q = l >> 4, c16 = l & 15;
  int n0 = w * 32;
  // B-frags: B[k][n] = R[n][k]; lane holds B[kt*32+q*8+j][n0+nt*16+c16], j=0..7
  short8 bh[2][8], bl[2][8];
#pragma unroll
  for (int nt = 0; nt < 2; nt++)
#pragma unroll
    for (int kt = 0; kt < 8; kt++) {
      size_t offs = (size_t)(n0 + nt * 16 + c16) * 256 + kt * 32 + q * 8;
      bh[nt][kt] = *(const short8*)(Mh + offs);
      bl[nt][kt] = *(const short8*)(Ml + offs);
    }
  __shared__ __attribute__((aligned(16))) ushort_t xh[2][32][16][8];  // [buf][k>>3][chain][k&7]
  __shared__ __attribute__((aligned(16))) ushort_t xl[2][32][16][8];
  __shared__ float hist[HSLOTS][16][256];
  // initial x (and row-0 store for MODE 2)
  for (int e = t; e < 1024; e += 512) {
    int c = e >> 6, qq = (e & 63) * 4;
    int cg = blk * 16 + c;
    float4 v4;
    if (MODE == 0) {
      v4 = make_float4(qq == cg ? 1.f : 0.f, qq + 1 == cg ? 1.f : 0.f,
                       qq + 2 == cg ? 1.f : 0.f, qq + 3 == cg ? 1.f : 0.f);
    } else if (MODE == 1) {
      v4 = *(const float4*)(V + (size_t)cg * 32 * 256 + qq);
    } else {
      v4 = *(const float4*)(X0 + (size_t)cg * 256 + qq);
      *(float4*)(Out + ((size_t)cg * 32) * 256 + qq) = v4;
    }
    float vals[4] = {v4.x, v4.y, v4.z, v4.w};
#pragma unroll
    for (int i = 0; i < 4; i++) {
      int n = qq + i;
      ushort_t h = bf16_hi(vals[i]);
      xh[0][n >> 3][c][n & 7] = h;
      xl[0][n >> 3][c][n & 7] = bf16_hi(vals[i] - bf16_f(h));
    }
  }
  // per-lane drive prefetch for step 1 (element (r,nt): chain q*4+r, col n0+nt*16+c16)
  float vnext[8];
  if (MODE != 0) {
#pragma unroll
    for (int r = 0; r < 4; r++)
#pragma unroll
      for (int nt = 0; nt < 2; nt++) {
        int cg = blk * 16 + q * 4 + r;
        int drow = (MODE == 1) ? 1 : 0;
        vnext[r * 2 + nt] = V[((size_t)cg * 32 + drow) * 256 + n0 + nt * 16 + c16];
      }
  }
  __syncthreads();
  for (int s = 1; s <= STEPS; s++) {
    int cur = (s - 1) & 1, nxt = s & 1;
    // MODE 2: flush rows s-4..s-1 (slots row%5) — reads race-free vs writes (mod-5 disjoint)
    if (MODE == 2 && s >= 5 && ((s - 1) & 3) == 0) {
      int rbase = s - 4;
      for (int e = t; e < 4096; e += 512) {
        int slot = e >> 10;
        int rem = e & 1023;
        int c = rem >> 6, qq = (rem & 63) * 4;
        int row = rbase + slot;
        int cg = blk * 16 + c;
        *(float4*)(Out + ((size_t)cg * 32 + row) * 256 + qq) = *(const float4*)&hist[row % 5][c][qq];
      }
    }
    // drive: consume prefetched, issue next step's loads (hidden under MFMAs)
    float vc[8];
    if (MODE != 0) {
#pragma unroll
      for (int i2 = 0; i2 < 8; i2++) vc[i2] = vnext[i2];
      if (s < STEPS) {
        int drow = (MODE == 1) ? (s + 1) : s;
#pragma unroll
        for (int r = 0; r < 4; r++)
#pragma unroll
          for (int nt = 0; nt < 2; nt++)
            vnext[r * 2 + nt] =
                V[((size_t)(blk * 16 + q * 4 + r) * 32 + drow) * 256 + n0 + nt * 16 + c16];
      }
    }
    // pin frags: rw asm operand => value must live in VGPRs, reload illegal
#pragma unroll
    for (int nt = 0; nt < 2; nt++)
#pragma unroll
      for (int kt = 0; kt < 8; kt++) {
        asm volatile("" : "+v"(bh[nt][kt]));
        asm volatile("" : "+v"(bl[nt][kt]));
      }
    float4v a0h = {0.f, 0.f, 0.f, 0.f}, a1h = {0.f, 0.f, 0.f, 0.f};
    float4v a0l = {0.f, 0.f, 0.f, 0.f}, a1l = {0.f, 0.f, 0.f, 0.f};
    float4v a0c = {0.f, 0.f, 0.f, 0.f}, a1c = {0.f, 0.f, 0.f, 0.f};
#pragma unroll
    for (int kt = 0; kt < 8; kt++) {
      short8 ah = *(const short8*)&xh[cur][kt * 4 + q][c16][0];
      short8 al = *(const short8*)&xl[cur][kt * 4 + q][c16][0];
      a0h = __builtin_amdgcn_mfma_f32_16x16x32_bf16(ah, bh[0][kt], a0h, 0, 0, 0);
      a1h = __builtin_amdgcn_mfma_f32_16x16x32_bf16(ah, bh[1][kt], a1h, 0, 0, 0);
      a0l = __builtin_amdgcn_mfma_f32_16x16x32_bf16(al, bh[0][kt], a0l, 0, 0, 0);
      a1l = __builtin_amdgcn_mfma_f32_16x16x32_bf16(al, bh[1][kt], a1l, 0, 0, 0);
      a0c = __builtin_amdgcn_mfma_f32_16x16x32_bf16(ah, bl[0][kt], a0c, 0, 0, 0);
      a1c = __builtin_amdgcn_mfma_f32_16x16x32_bf16(ah, bl[1][kt], a1c, 0, 0, 0);
    }
    // epilogue: C/D layout chain=(q*4+r), col=c16 (m89-verified)
#pragma unroll
    for (int nt = 0; nt < 2; nt++) {
#pragma unroll
      for (int r = 0; r < 4; r++) {
        int c = q * 4 + r;
        int n = n0 + nt * 16 + c16;
        float val = (nt == 0) ? (a0h[r] + a0l[r] + a0c[r]) : (a1h[r] + a1l[r] + a1c[r]);
        if (MODE != 0) val += vc[r * 2 + nt];
        int cg = blk * 16 + c;
        if (MODE == 2) hist[s % 5][c][n] = val;
        if (MODE == 1 && s == STEPS) Out[(size_t)cg * 256 + n] = val;
        if (MODE == 0 && s == STEPS) {
          ushort_t h2 = bf16_hi(val);
          Out[(size_t)n * 256 + cg] = val;
          OutH[(size_t)n * 256 + cg] = h2;
          OutL[(size_t)n * 256 + cg] = bf16_hi(val - bf16_f(h2));
        }
        ushort_t h = bf16_hi(val);
        xh[nxt][n >> 3][c][n & 7] = h;
        xl[nxt][n >> 3][c][n & 7] = bf16_hi(val - bf16_f(h));
      }
    }
    __syncthreads();
  }
  if (MODE == 2) {   // final rows 29,30,31
    for (int e = t; e < 3072; e += 512) {
      int slot = e >> 10;
      int rem = e & 1023;
      int c = rem >> 6, qq = (rem & 63) * 4;
      int row = 29 + slot;
      int cg = blk * 16 + c;
      *(float4*)(Out + ((size_t)cg * 32 + row) * 256 + qq) = *(const float4*)&hist[row % 5][c][qq];
    }
  }
}

// ---------------------------------------------------------------------------
// fp32 GEMM for the drive: C[M][256] = A[M][K] @ B[K][256], BM=BN=128, BK=8.
__global__ __launch_bounds__(256) void gemm128(const float* __restrict__ A, const float* __restrict__ B,
                                               float* __restrict__ C, int M, int K) {
  int m0 = blockIdx.x * 128, n0 = blockIdx.y * 128;
  __shared__ float As[8][128];
  __shared__ float Bs[8][128];
  int tid = threadIdx.x;
  int am = tid >> 1, akc = (tid & 1) * 4;
  int bk = tid >> 5, bn = (tid & 31) * 4;
  int ty = tid >> 4, tx = tid & 15;
  float acc[8][8] = {{0.f}};
  for (int kt = 0; kt < K; kt += 8) {
    float4 av = make_float4(0.f, 0.f, 0.f, 0.f);
    if (m0 + am < M) av = *(const float4*)(A + (size_t)(m0 + am) * K + kt + akc);
    float4 bv = *(const float4*)(B + (size_t)(kt + bk) * 256 + n0 + bn);
    __syncthreads();
    As[akc + 0][am] = av.x;
    As[akc + 1][am] = av.y;
    As[akc + 2][am] = av.z;
    As[akc + 3][am] = av.w;
    *(float4*)&Bs[bk][bn] = bv;
    __syncthreads();
#pragma unroll
    for (int kk = 0; kk < 8; kk++) {
      float4 a0 = *(const float4*)&As[kk][ty * 8];
      float4 a1 = *(const float4*)&As[kk][ty * 8 + 4];
      float4 b0 = *(const float4*)&Bs[kk][tx * 8];
      float4 b1 = *(const float4*)&Bs[kk][tx * 8 + 4];
      float ar[8] = {a0.x, a0.y, a0.z, a0.w, a1.x, a1.y, a1.z, a1.w};
      float br[8] = {b0.x, b0.y, b0.z, b0.w, b1.x, b1.y, b1.z, b1.w};
#pragma unroll
      for (int i = 0; i < 8; i++)
#pragma unroll
        for (int j = 0; j < 8; j++) acc[i][j] += ar[i] * br[j];
    }
  }
#pragma unroll
  for (int i = 0; i < 8; i++) {
    int row = m0 + ty * 8 + i;
    if (row < M) {
      *(float4*)&C[(size_t)row * 256 + n0 + tx * 8] = make_float4(acc[i][0], acc[i][1], acc[i][2], acc[i][3]);
      *(float4*)&C[(size_t)row * 256 + n0 + tx * 8 + 4] = make_float4(acc[i][4], acc[i][5], acc[i][6], acc[i][7]);
    }
  }
}

// AT = A^T (256x256)
__global__ __launch_bounds__(256) void transpose_at(const float* __restrict__ A, float* __restrict__ AT) {
  __shared__ float tile[64][65];
  int bx = blockIdx.x & 3, by = blockIdx.x >> 2;
  int r0 = by * 64, c0 = bx * 64;
  int t = threadIdx.x;
  int lr = t >> 4, lc = (t & 15) * 4;
  for (int rr = lr; rr < 64; rr += 16) {
    float4 v = *(const float4*)(A + (size_t)(r0 + rr) * 256 + c0 + lc);
    tile[rr][lc + 0] = v.x; tile[rr][lc + 1] = v.y; tile[rr][lc + 2] = v.z; tile[rr][lc + 3] = v.w;
  }
  __syncthreads();
  for (int rr = lr; rr < 64; rr += 16) {
    float4 v = make_float4(tile[lc + 0][rr], tile[lc + 1][rr], tile[lc + 2][rr], tile[lc + 3][rr]);
    *(float4*)(AT + (size_t)(c0 + rr) * 256 + r0 + lc) = v;
  }
}

// Unit responses through one Dopri5 step: cols 0..255 -> R fp32 + bf16 hi/lo
// split; cols 256..383 -> Hermite-folded tap matrices transposed into FcatT.
__global__ __launch_bounds__(256) void unit_resp(const float* __restrict__ AT,
                                                 const float* __restrict__ Bm,
                                                 float* __restrict__ Rout,
                                                 ushort_t* __restrict__ Rh,
                                                 ushort_t* __restrict__ Rl,
                                                 float* __restrict__ FcatT) {
  int w = blockIdx.x;
  int i = threadIdx.x;
  __shared__ float xs4[256][4];

  const float AA[6][5] = {
      {0.f, 0.f, 0.f, 0.f, 0.f},
      {0.2f, 0.f, 0.f, 0.f, 0.f},
      {3.f / 40.f, 9.f / 40.f, 0.f, 0.f, 0.f},
      {44.f / 45.f, -56.f / 15.f, 32.f / 9.f, 0.f, 0.f},
      {19372.f / 6561.f, -25360.f / 2187.f, 64448.f / 6561.f, -212.f / 729.f, 0.f},
      {9017.f / 3168.f, -355.f / 33.f, 46732.f / 5247.f, 49.f / 176.f, -5103.f / 18656.f}};
  const float BB[6] = {35.f / 384.f, 0.f, 500.f / 1113.f, 125.f / 192.f, -2187.f / 6784.f, 11.f / 84.f};
  const float sv[6] = {0.f, 0.2f, 0.3f, 0.8f, 8.f / 9.f, 1.f};
  float Hm[6][4];
#pragma unroll
  for (int s = 0; s < 6; s++) {
    float ss = sv[s], s2 = ss * ss, s3 = s2 * ss;
    Hm[s][0] = 2.f * s3 - 3.f * s2 + 1.f;
    Hm[s][1] = s3 - 2.f * s2 + ss;
    Hm[s][2] = -2.f * s3 + 3.f * s2;
    Hm[s][3] = s3 - s2;
  }

  float xc[4];
  float kreg[6][4];
#pragma unroll
  for (int s = 0; s < 6; s++)
#pragma unroll
    for (int cc = 0; cc < 4; cc++) kreg[s][cc] = 0.f;

  int col[4], isF[4], tt[4];
  float brow[4];
#pragma unroll
  for (int cc = 0; cc < 4; cc++) {
    col[cc] = w * 4 + cc;
    if (col[cc] < 256) {
      isF[cc] = 0; tt[cc] = 0; brow[cc] = 0.f;
      xc[cc] = (i == col[cc]) ? 1.f : 0.f;
    } else {
      isF[cc] = 1; xc[cc] = 0.f;
      int f = col[cc] - 256;
      tt[cc] = f >> 5;
      brow[cc] = Bm[i * 32 + (f & 31)];
    }
  }
  float bh[6][4];
#pragma unroll
  for (int s = 0; s < 6; s++)
#pragma unroll
    for (int cc = 0; cc < 4; cc++) {
      float hv = (tt[cc] == 0) ? Hm[s][0] : ((tt[cc] == 1) ? Hm[s][1] : ((tt[cc] == 2) ? Hm[s][2] : Hm[s][3]));
      bh[s][cc] = isF[cc] ? hv * brow[cc] : 0.f;
    }

#pragma unroll
  for (int s = 0; s < 6; s++) {
#pragma unroll
    for (int cc = 0; cc < 4; cc++) {
      float v = xc[cc];
#pragma unroll
      for (int j = 0; j < 5; j++)
        if (j < s) v += AA[s][j] * kreg[j][cc];
      xs4[i][cc] = v;
    }
    __syncthreads();
    float ac[4] = {0.f, 0.f, 0.f, 0.f};
#pragma unroll 4
    for (int j = 0; j < 256; j++) {
      float a = AT[(size_t)j * 256 + i];
      float4 xv = *(const float4*)xs4[j];
      ac[0] += a * xv.x;
      ac[1] += a * xv.y;
      ac[2] += a * xv.z;
      ac[3] += a * xv.w;
    }
#pragma unroll
    for (int cc = 0; cc < 4; cc++) kreg[s][cc] = ac[cc] + bh[s][cc];
    __syncthreads();
  }
#pragma unroll
  for (int cc = 0; cc < 4; cc++) {
    float o = xc[cc];
#pragma unroll
    for (int s = 0; s < 6; s++) o += BB[s] * kreg[s][cc];
    if (!isF[cc]) {
      Rout[(size_t)i * 256 + col[cc]] = o;
      ushort_t h = bf16_hi(o);
      Rh[(size_t)i * 256 + col[cc]] = h;
      Rl[(size_t)i * 256 + col[cc]] = bf16_hi(o - bf16_f(h));
    } else {
      FcatT[(size_t)(col[cc] - 256) * 256 + i] = o;
    }
  }
}

// Wtap[n][tap] = {u_n, m_n, u_{n+1}, m_{n+1}} taps; row 32767 = 0 (pad).
__global__ __launch_bounds__(128) void build_wtap(const float* __restrict__ u, float* __restrict__ Wtap) {
  int n = blockIdx.x;
  int tid = threadIdx.x;
  int t = tid >> 5, c = tid & 31;
  float val = 0.f;
  if (n < TPTS - 1) {
    if (t == 0) val = u[(size_t)n * 32 + c];
    else if (t == 2) val = u[(size_t)(n + 1) * 32 + c];
    else {
      int k = (t == 1) ? n : n + 1;
      if (k == 0) val = u[32 + c] - u[c];
      else if (k == TPTS - 1) val = u[(size_t)(TPTS - 1) * 32 + c] - u[(size_t)(TPTS - 2) * 32 + c];
      else val = 0.5f * (u[(size_t)(k + 1) * 32 + c] - u[(size_t)(k - 1) * 32 + c]);
    }
  }
  Wtap[(size_t)n * 128 + tid] = val;
}

// Top-level (stride-1024) starts; ||R^1024|| ~ 6e-5 so 2-term series suffices.
__global__ __launch_bounds__(256) void top_scan(const float* __restrict__ V2, const float* __restrict__ x0,
                                                const float* __restrict__ R1024, float* __restrict__ X2) {
  int k = blockIdx.x, i = threadIdx.x;
  if (k == 0) { X2[i] = x0[i]; return; }
  __shared__ float prev[256];
  const float* pv = (k == 1) ? x0 : (V2 + (size_t)(k - 2) * 256);
  prev[i] = pv[i];
  __syncthreads();
  float acc = V2[(size_t)(k - 1) * 256 + i];
  const float* rr = R1024 + (size_t)i * 256;
  for (int j = 0; j < 256; j += 4) {
    float4 rv = *(const float4*)(rr + j);
    acc += rv.x * prev[j] + rv.y * prev[j + 1] + rv.z * prev[j + 2] + rv.w * prev[j + 3];
  }
  X2[(size_t)k * 256 + i] = acc;
}

// y = x @ C^T + u @ D^T
__global__ __launch_bounds__(256) void y_kernel(const float* __restrict__ x, const float* __restrict__ u,
                                                const float* __restrict__ Cm, const float* __restrict__ Dm,
                                                float* __restrict__ y) {
  __shared__ float Cs[32][260];
  __shared__ float Ds[32][32];
  __shared__ float xs[8][256];
  __shared__ float us[8][32];
  int tid = threadIdx.x;
  for (int k = tid; k < 8192; k += 256) Cs[k >> 8][k & 255] = Cm[k];
  for (int k = tid; k < 1024; k += 256) Ds[k >> 5][k & 31] = Dm[k];
  int o = tid & 31, rr = tid >> 5;
  int n0 = blockIdx.x * 64;
  for (int g = 0; g < 8; g++) {
    int nb = n0 + g * 8;
    __syncthreads();
    for (int k = tid; k < 2048; k += 256)
      xs[k >> 8][k & 255] = x[(size_t)(nb + (k >> 8)) * 256 + (k & 255)];
    for (int k = tid; k < 256; k += 256)
      us[k >> 5][k & 31] = u[(size_t)(nb + (k >> 5)) * 32 + (k & 31)];
    __syncthreads();
    float acc = 0.f;
    for (int i = 0; i < 256; i += 4) {
      float4 cv = *(const float4*)&Cs[o][i];
      float4 xv = *(const float4*)&xs[rr][i];
      acc += cv.x * xv.x + cv.y * xv.y + cv.z * xv.z + cv.w * xv.w;
    }
#pragma unroll
    for (int c = 0; c < 32; c += 4) {
      float4 dv = *(const float4*)&Ds[o][c];
      float4 uv = *(const float4*)&us[rr][c];
      acc += dv.x * uv.x + dv.y * uv.y + dv.z * uv.z + dv.w * uv.w;
    }
    y[(size_t)(nb + rr) * 32 + o] = acc;
  }
}

extern "C" void kernel_launch(void* const* d_in, const int* in_sizes, int n_in,
                              void* d_out, int out_size, void* d_ws, size_t ws_size,
                              hipStream_t stream) {
  const float* u  = (const float*)d_in[1];
  const float* x0 = (const float*)d_in[2];
  const float* A  = (const float*)d_in[3];
  const float* Bm = (const float*)d_in[4];
  const float* Cm = (const float*)d_in[5];
  const float* Dm = (const float*)d_in[6];
  float* xout = (float*)d_out;                       // [32768][256]
  float* yout = xout + (size_t)TPTS * 256;           // [32768][32]

  char* wsb = (char*)d_ws;
  size_t off = 0;
  auto alloc = [&](size_t bytes) -> void* {
    void* p = (void*)(wsb + off);
    off = (off + bytes + 255) & ~(size_t)255;
    return p;
  };
  float*    Rfp    = (float*)alloc(65536 * 4);
  ushort_t* Rh     = (ushort_t*)alloc(65536 * 2);
  ushort_t* Rl     = (ushort_t*)alloc(65536 * 2);
  float*    R32fp  = (float*)alloc(65536 * 4);
  ushort_t* R32h   = (ushort_t*)alloc(65536 * 2);
  ushort_t* R32l   = (ushort_t*)alloc(65536 * 2);
  float*    RKfp   = (float*)alloc(65536 * 4);       // R^1024
  ushort_t* RKh    = (ushort_t*)alloc(65536 * 2);
  ushort_t* RKl    = (ushort_t*)alloc(65536 * 2);
  float*    ATm    = (float*)alloc(65536 * 4);
  float*    FcatT  = (float*)alloc(128 * 256 * 4);
  float*    Wtap   = (float*)alloc((size_t)TPTS * 128 * 4);
  float*    V0     = (float*)alloc((size_t)TPTS * 256 * 4);
  float*    V1     = (float*)alloc(1024 * 256 * 4);
  float*    V2     = (float*)alloc(32 * 256 * 4);
  float*    X2     = (float*)alloc(32 * 256 * 4);
  float*    X1     = (float*)alloc(1024 * 256 * 4);
  (void)ws_size; (void)in_sizes; (void)n_in; (void)out_size;

  // 1. A^T, unit responses -> R (fp32 + hi/lo split) and FcatT
  transpose_at<<<dim3(16), dim3(256), 0, stream>>>(A, ATm);
  unit_resp<<<dim3(96), dim3(256), 0, stream>>>(ATm, Bm, Rfp, Rh, Rl, FcatT);

  // 2. R^32 = 32 chained applications of R on unit columns; R^1024 likewise on R^32
  chain_mfma<0><<<dim3(16), dim3(512), 0, stream>>>(Rh, Rl, nullptr, nullptr, R32fp, R32h, R32l);
  chain_mfma<0><<<dim3(16), dim3(512), 0, stream>>>(R32h, R32l, nullptr, nullptr, RKfp, RKh, RKl);

  // 3. Hermite taps and per-step drive v_n (fp32 GEMM, K=128)
  build_wtap<<<dim3(TPTS), dim3(128), 0, stream>>>(u, Wtap);
  gemm128<<<dim3(256, 2), dim3(256), 0, stream>>>(Wtap, FcatT, V0, TPTS, 128);

  // 4. reduces: V1[j] = sum_i R^(31-i) v_{32j+i};  V2[k] = sum_j R32^(31-j) V1[32k+j]
  chain_mfma<1><<<dim3(64), dim3(512), 0, stream>>>(Rh, Rl, nullptr, V0, V1, nullptr, nullptr);
  chain_mfma<1><<<dim3(2), dim3(512), 0, stream>>>(R32h, R32l, nullptr, V1, V2, nullptr, nullptr);

  // 5. top starts, then expand down two levels
  top_scan<<<dim3(32), dim3(256), 0, stream>>>(V2, x0, RKfp, X2);
  chain_mfma<2><<<dim3(2), dim3(512), 0, stream>>>(R32h, R32l, X2, V1, X1, nullptr, nullptr);
  chain_mfma<2><<<dim3(64), dim3(512), 0, stream>>>(Rh, Rl, X1, V0, xout, nullptr, nullptr);

  // 6. outputs y
  y_kernel<<<dim3(512), dim3(256), 0, stream>>>(xout, u, Cm, Dm, yout);
}

// Round 2
// 480.298 us; speedup vs baseline: 1.0870x; 1.0870x over previous
//
#include <hip/hip_runtime.h>

// Flow_49160195670664: Dopri5 fixed-step integration of dx/dt = A x + B u(t),
// T=32768, N=256, NI=NO=32, dt=1, Hermite-interpolated stage inputs.
// Linear system => x_{n+1} = R x_n + v_n with constant R; 2-level blocked
// parallel scan (32 x 32 x 32). Sequential-chain parts run on MFMA with
// bf16 hi/lo split (x*R ~ xh*Rh + xl*Rh + xh*Rl, fp32 accumulate).

#define TPTS 32768

typedef __attribute__((ext_vector_type(8))) short short8;
typedef __attribute__((ext_vector_type(4))) float float4v;
typedef unsigned short ushort_t;

__device__ __forceinline__ ushort_t bf16_hi(float f) {
  unsigned u = __builtin_bit_cast(unsigned, f);
  unsigned r = (u + 0x7FFFu + ((u >> 16) & 1u)) >> 16;
  return (ushort_t)r;
}
__device__ __forceinline__ float bf16_f(ushort_t h) {
  unsigned u = ((unsigned)h) << 16;
  return __builtin_bit_cast(float, u);
}

// ---------------------------------------------------------------------------
// MFMA chain kernel v2. 512 thr = 8 waves; wave w owns output cols [32w,32w+32)
// as 2 N-tiles of mfma_f32_16x16x32_bf16; 16 chains = MFMA M-dim.
// R^T B-frags live in VGPRs, residency FORCED by per-value "+v" asm pins inside
// the loop (a rw-operand makes reload/remat illegal — the r2-r6 lesson; plain
// memory clobbers don't stop rematerialization, VGPR_Count was 88 not ~190).
// 6 independent accumulators cut dependent-MFMA depth 24 -> 8.
// V-drive is per-lane register-prefetched one step ahead (no vbuf LDS/barrier).
// MODE 2 stores go through a 5-slot LDS ring, flushed 4 rows per 4 steps just
// after a barrier so the global-store drain overlaps the next step's MFMAs.
// MODE 0: power  (32 steps, x0 = I cols; Out=R^32 row-major fp32 + h/l split)
// MODE 1: reduce (31 steps, x0 = V row0, drive rows 1..31; Out[chain] = final x)
// MODE 2: expand (31 steps, x0 = X0, drive rows 0..30; Out rows chain*32+j)
template <int MODE>
__global__ __launch_bounds__(512, 2) void chain_mfma(const ushort_t* Mh, const ushort_t* Ml,
                                                     const float* X0, const float* V,
                                                     float* Out, ushort_t* OutH, ushort_t* OutL) {
  constexpr int STEPS = (MODE == 0) ? 32 : 31;
  constexpr int HSLOTS = (MODE == 2) ? 5 : 1;
  int blk = blockIdx.x, t = threadIdx.x;
  int w = t >> 6, l = t & 63;
  int q = l >> 4, c16 = l & 15;
  int n0 = w * 32;
  // B-frags: B[k][n] = R[n][k]; lane holds B[kt*32+q*8+j][n0+nt*16+c16], j=0..7
  short8 bh[2][8], bl[2][8];
#pragma unroll
  for (int nt = 0; nt < 2; nt++)
#pragma unroll
    for (int kt = 0; kt < 8; kt++) {
      size_t offs = (size_t)(n0 + nt * 16 + c16) * 256 + kt * 32 + q * 8;
      bh[nt][kt] = *(const short8*)(Mh + offs);
      bl[nt][kt] = *(const short8*)(Ml + offs);
    }
  __shared__ __attribute__((aligned(16))) ushort_t xh[2][32][16][8];  // [buf][k>>3][chain][k&7]
  __shared__ __attribute__((aligned(16))) ushort_t xl[2][32][16][8];
  __shared__ float hist[HSLOTS][16][256];
  // initial x (and row-0 store for MODE 2)
  for (int e = t; e < 1024; e += 512) {
    int c = e >> 6, qq = (e & 63) * 4;
    int cg = blk * 16 + c;
    float4 v4;
    if (MODE == 0) {
      v4 = make_float4(qq == cg ? 1.f : 0.f, qq + 1 == cg ? 1.f : 0.f,
                       qq + 2 == cg ? 1.f : 0.f, qq + 3 == cg ? 1.f : 0.f);
    } else if (MODE == 1) {
      v4 = *(const float4*)(V + (size_t)cg * 32 * 256 + qq);
    } else {
      v4 = *(const float4*)(X0 + (size_t)cg * 256 + qq);
      *(float4*)(Out + ((size_t)cg * 32) * 256 + qq) = v4;
    }
    float vals[4] = {v4.x, v4.y, v4.z, v4.w};
#pragma unroll
    for (int i = 0; i < 4; i++) {
      int n = qq + i;
      ushort_t h = bf16_hi(vals[i]);
      xh[0][n >> 3][c][n & 7] = h;
      xl[0][n >> 3][c][n & 7] = bf16_hi(vals[i] - bf16_f(h));
    }
  }
  // per-lane drive prefetch for step 1 (element (r,nt): chain q*4+r, col n0+nt*16+c16)
  float vnext[8];
  if (MODE != 0) {
#pragma unroll
    for (int r = 0; r < 4; r++)
#pragma unroll
      for (int nt = 0; nt < 2; nt++) {
        int cg = blk * 16 + q * 4 + r;
        int drow = (MODE == 1) ? 1 : 0;
        vnext[r * 2 + nt] = V[((size_t)cg * 32 + drow) * 256 + n0 + nt * 16 + c16];
      }
  }
  __syncthreads();
  for (int s = 1; s <= STEPS; s++) {
    int cur = (s - 1) & 1, nxt = s & 1;
    // MODE 2: flush rows s-4..s-1 (slots row%5) — reads race-free vs writes (mod-5 disjoint)
    if (MODE == 2 && s >= 5 && ((s - 1) & 3) == 0) {
      int rbase = s - 4;
      for (int e = t; e < 4096; e += 512) {
        int slot = e >> 10;
        int rem = e & 1023;
        int c = rem >> 6, qq = (rem & 63) * 4;
        int row = rbase + slot;
        int cg = blk * 16 + c;
        *(float4*)(Out + ((size_t)cg * 32 + row) * 256 + qq) = *(const float4*)&hist[row % 5][c][qq];
      }
    }
    // drive: consume prefetched, issue next step's loads (hidden under MFMAs)
    float vc[8];
    if (MODE != 0) {
#pragma unroll
      for (int i2 = 0; i2 < 8; i2++) vc[i2] = vnext[i2];
      if (s < STEPS) {
        int drow = (MODE == 1) ? (s + 1) : s;
#pragma unroll
        for (int r = 0; r < 4; r++)
#pragma unroll
          for (int nt = 0; nt < 2; nt++)
            vnext[r * 2 + nt] =
                V[((size_t)(blk * 16 + q * 4 + r) * 32 + drow) * 256 + n0 + nt * 16 + c16];
      }
    }
    // pin frags: rw asm operand => value must live in VGPRs, reload illegal
#pragma unroll
    for (int nt = 0; nt < 2; nt++)
#pragma unroll
      for (int kt = 0; kt < 8; kt++) {
        asm volatile("" : "+v"(bh[nt][kt]));
        asm volatile("" : "+v"(bl[nt][kt]));
      }
    float4v a0h = {0.f, 0.f, 0.f, 0.f}, a1h = {0.f, 0.f, 0.f, 0.f};
    float4v a0l = {0.f, 0.f, 0.f, 0.f}, a1l = {0.f, 0.f, 0.f, 0.f};
    float4v a0c = {0.f, 0.f, 0.f, 0.f}, a1c = {0.f, 0.f, 0.f, 0.f};
#pragma unroll
    for (int kt = 0; kt < 8; kt++) {
      short8 ah = *(const short8*)&xh[cur][kt * 4 + q][c16][0];
      short8 al = *(const short8*)&xl[cur][kt * 4 + q][c16][0];
      a0h = __builtin_amdgcn_mfma_f32_16x16x32_bf16(ah, bh[0][kt], a0h, 0, 0, 0);
      a1h = __builtin_amdgcn_mfma_f32_16x16x32_bf16(ah, bh[1][kt], a1h, 0, 0, 0);
      a0l = __builtin_amdgcn_mfma_f32_16x16x32_bf16(al, bh[0][kt], a0l, 0, 0, 0);
      a1l = __builtin_amdgcn_mfma_f32_16x16x32_bf16(al, bh[1][kt], a1l, 0, 0, 0);
      a0c = __builtin_amdgcn_mfma_f32_16x16x32_bf16(ah, bl[0][kt], a0c, 0, 0, 0);
      a1c = __builtin_amdgcn_mfma_f32_16x16x32_bf16(ah, bl[1][kt], a1c, 0, 0, 0);
    }
    // epilogue: C/D layout chain=(q*4+r), col=c16 (m89-verified)
#pragma unroll
    for (int nt = 0; nt < 2; nt++) {
#pragma unroll
      for (int r = 0; r < 4; r++) {
        int c = q * 4 + r;
        int n = n0 + nt * 16 + c16;
        float val = (nt == 0) ? (a0h[r] + a0l[r] + a0c[r]) : (a1h[r] + a1l[r] + a1c[r]);
        if (MODE != 0) val += vc[r * 2 + nt];
        int cg = blk * 16 + c;
        if (MODE == 2) hist[s % 5][c][n] = val;
        if (MODE == 1 && s == STEPS) Out[(size_t)cg * 256 + n] = val;
        if (MODE == 0 && s == STEPS) {
          ushort_t h2 = bf16_hi(val);
          Out[(size_t)n * 256 + cg] = val;
          OutH[(size_t)n * 256 + cg] = h2;
          OutL[(size_t)n * 256 + cg] = bf16_hi(val - bf16_f(h2));
        }
        ushort_t h = bf16_hi(val);
        xh[nxt][n >> 3][c][n & 7] = h;
        xl[nxt][n >> 3][c][n & 7] = bf16_hi(val - bf16_f(h));
      }
    }
    __syncthreads();
  }
  if (MODE == 2) {   // final rows 29,30,31
    for (int e = t; e < 3072; e += 512) {
      int slot = e >> 10;
      int rem = e & 1023;
      int c = rem >> 6, qq = (rem & 63) * 4;
      int row = 29 + slot;
      int cg = blk * 16 + c;
      *(float4*)(Out + ((size_t)cg * 32 + row) * 256 + qq) = *(const float4*)&hist[row % 5][c][qq];
    }
  }
}

// ---------------------------------------------------------------------------
// fp32 GEMM for the drive: C[M][256] = A[M][K] @ B[K][256], BM=BN=128, BK=8.
__global__ __launch_bounds__(256) void gemm128(const float* __restrict__ A, const float* __restrict__ B,
                                               float* __restrict__ C, int M, int K) {
  int m0 = blockIdx.x * 128, n0 = blockIdx.y * 128;
  __shared__ float As[8][128];
  __shared__ float Bs[8][128];
  int tid = threadIdx.x;
  int am = tid >> 1, akc = (tid & 1) * 4;
  int bk = tid >> 5, bn = (tid & 31) * 4;
  int ty = tid >> 4, tx = tid & 15;
  float acc[8][8] = {{0.f}};
  for (int kt = 0; kt < K; kt += 8) {
    float4 av = make_float4(0.f, 0.f, 0.f, 0.f);
    if (m0 + am < M) av = *(const float4*)(A + (size_t)(m0 + am) * K + kt + akc);
    float4 bv = *(const float4*)(B + (size_t)(kt + bk) * 256 + n0 + bn);
    __syncthreads();
    As[akc + 0][am] = av.x;
    As[akc + 1][am] = av.y;
    As[akc + 2][am] = av.z;
    As[akc + 3][am] = av.w;
    *(float4*)&Bs[bk][bn] = bv;
    __syncthreads();
#pragma unroll
    for (int kk = 0; kk < 8; kk++) {
      float4 a0 = *(const float4*)&As[kk][ty * 8];
      float4 a1 = *(const float4*)&As[kk][ty * 8 + 4];
      float4 b0 = *(const float4*)&Bs[kk][tx * 8];
      float4 b1 = *(const float4*)&Bs[kk][tx * 8 + 4];
      float ar[8] = {a0.x, a0.y, a0.z, a0.w, a1.x, a1.y, a1.z, a1.w};
      float br[8] = {b0.x, b0.y, b0.z, b0.w, b1.x, b1.y, b1.z, b1.w};
#pragma unroll
      for (int i = 0; i < 8; i++)
#pragma unroll
        for (int j = 0; j < 8; j++) acc[i][j] += ar[i] * br[j];
    }
  }
#pragma unroll
  for (int i = 0; i < 8; i++) {
    int row = m0 + ty * 8 + i;
    if (row < M) {
      *(float4*)&C[(size_t)row * 256 + n0 + tx * 8] = make_float4(acc[i][0], acc[i][1], acc[i][2], acc[i][3]);
      *(float4*)&C[(size_t)row * 256 + n0 + tx * 8 + 4] = make_float4(acc[i][4], acc[i][5], acc[i][6], acc[i][7]);
    }
  }
}

// AT = A^T (256x256)
__global__ __launch_bounds__(256) void transpose_at(const float* __restrict__ A, float* __restrict__ AT) {
  __shared__ float tile[64][65];
  int bx = blockIdx.x & 3, by = blockIdx.x >> 2;
  int r0 = by * 64, c0 = bx * 64;
  int t = threadIdx.x;
  int lr = t >> 4, lc = (t & 15) * 4;
  for (int rr = lr; rr < 64; rr += 16) {
    float4 v = *(const float4*)(A + (size_t)(r0 + rr) * 256 + c0 + lc);
    tile[rr][lc + 0] = v.x; tile[rr][lc + 1] = v.y; tile[rr][lc + 2] = v.z; tile[rr][lc + 3] = v.w;
  }
  __syncthreads();
  for (int rr = lr; rr < 64; rr += 16) {
    float4 v = make_float4(tile[lc + 0][rr], tile[lc + 1][rr], tile[lc + 2][rr], tile[lc + 3][rr]);
    *(float4*)(AT + (size_t)(c0 + rr) * 256 + r0 + lc) = v;
  }
}

// Unit responses through one Dopri5 step: cols 0..255 -> R fp32 + bf16 hi/lo
// split; cols 256..383 -> Hermite-folded tap matrices transposed into FcatT.
// v2: 1024 threads = 4 j-groups x 256 rows; 4-way split-K with LDS reduce.
// Thread (jg,i) owns column cc=jg of the block's 4 columns and keeps its
// kreg[6] stage slopes in registers; j-slices are disjoint so A-traffic per
// block per stage stays 256KB. 2 barriers/stage. (was: 256 thr, 1.5 waves/CU,
// 61us latency-bound at 3.5% VALUBusy)
__global__ __launch_bounds__(1024) void unit_resp(const float* __restrict__ AT,
                                                  const float* __restrict__ Bm,
                                                  float* __restrict__ Rout,
                                                  ushort_t* __restrict__ Rh,
                                                  ushort_t* __restrict__ Rl,
                                                  float* __restrict__ FcatT) {
  int blk = blockIdx.x;
  int tid = threadIdx.x;
  int jg = tid >> 8;   // j-group 0..3, also the owned column index cc
  int i = tid & 255;   // output row
  int cc = jg;
  int col = blk * 4 + cc;

  __shared__ float xs4[256][4];
  __shared__ float4 part[4][256];

  const float AA[6][5] = {
      {0.f, 0.f, 0.f, 0.f, 0.f},
      {0.2f, 0.f, 0.f, 0.f, 0.f},
      {3.f / 40.f, 9.f / 40.f, 0.f, 0.f, 0.f},
      {44.f / 45.f, -56.f / 15.f, 32.f / 9.f, 0.f, 0.f},
      {19372.f / 6561.f, -25360.f / 2187.f, 64448.f / 6561.f, -212.f / 729.f, 0.f},
      {9017.f / 3168.f, -355.f / 33.f, 46732.f / 5247.f, 49.f / 176.f, -5103.f / 18656.f}};
  const float BB[6] = {35.f / 384.f, 0.f, 500.f / 1113.f, 125.f / 192.f, -2187.f / 6784.f, 11.f / 84.f};
  const float sv[6] = {0.f, 0.2f, 0.3f, 0.8f, 8.f / 9.f, 1.f};
  float Hm[6][4];
#pragma unroll
  for (int s = 0; s < 6; s++) {
    float ss = sv[s], s2 = ss * ss, s3 = s2 * ss;
    Hm[s][0] = 2.f * s3 - 3.f * s2 + 1.f;
    Hm[s][1] = s3 - 2.f * s2 + ss;
    Hm[s][2] = -2.f * s3 + 3.f * s2;
    Hm[s][3] = s3 - s2;
  }

  // owned-column metadata
  int isF, tt;
  float brow, xc;
  if (col < 256) {
    isF = 0; tt = 0; brow = 0.f;
    xc = (i == col) ? 1.f : 0.f;
  } else {
    isF = 1; xc = 0.f;
    int f = col - 256;
    tt = f >> 5;
    brow = Bm[i * 32 + (f & 31)];
  }
  float bh[6];
#pragma unroll
  for (int s = 0; s < 6; s++) {
    float hv = (tt == 0) ? Hm[s][0] : ((tt == 1) ? Hm[s][1] : ((tt == 2) ? Hm[s][2] : Hm[s][3]));
    bh[s] = isF ? hv * brow : 0.f;
  }

  float kreg[6];
#pragma unroll
  for (int s = 0; s < 6; s++) kreg[s] = 0.f;

  int j0 = jg * 64;
#pragma unroll 1
  for (int s = 0; s < 6; s++) {
    // stage input for the owned column (register k's -> LDS)
    float xsv = xc;
#pragma unroll
    for (int j = 0; j < 5; j++)
      if (j < s) xsv += AA[s][j] * kreg[j];
    xs4[i][cc] = xsv;
    __syncthreads();
    // partial matvec over this thread's 64-row j-slice (4 cols per load)
    float acx = 0.f, acy = 0.f, acz = 0.f, acw = 0.f;
#pragma unroll 8
    for (int jj = 0; jj < 64; jj++) {
      int j = j0 + jj;
      float a = AT[(size_t)j * 256 + i];
      float4 xv = *(const float4*)xs4[j];
      acx += a * xv.x;
      acy += a * xv.y;
      acz += a * xv.z;
      acw += a * xv.w;
    }
    part[jg][i] = make_float4(acx, acy, acz, acw);
    __syncthreads();
    // owner reduces the 4 partials for its column
    float k = bh[s];
#pragma unroll
    for (int g = 0; g < 4; g++) {
      const float* p = (const float*)&part[g][i];
      k += p[cc];
    }
    kreg[s] = k;
    // no barrier needed: next stage's xs4 write is fenced by the barrier
    // after it, and part[] is only rewritten after that barrier too.
  }

  float o = xc;
#pragma unroll
  for (int s = 0; s < 6; s++) o += BB[s] * kreg[s];
  if (!isF) {
    Rout[(size_t)i * 256 + col] = o;
    ushort_t h = bf16_hi(o);
    Rh[(size_t)i * 256 + col] = h;
    Rl[(size_t)i * 256 + col] = bf16_hi(o - bf16_f(h));
  } else {
    FcatT[(size_t)(col - 256) * 256 + i] = o;
  }
}

// Wtap[n][tap] = {u_n, m_n, u_{n+1}, m_{n+1}} taps; row 32767 = 0 (pad).
__global__ __launch_bounds__(128) void build_wtap(const float* __restrict__ u, float* __restrict__ Wtap) {
  int n = blockIdx.x;
  int tid = threadIdx.x;
  int t = tid >> 5, c = tid & 31;
  float val = 0.f;
  if (n < TPTS - 1) {
    if (t == 0) val = u[(size_t)n * 32 + c];
    else if (t == 2) val = u[(size_t)(n + 1) * 32 + c];
    else {
      int k = (t == 1) ? n : n + 1;
      if (k == 0) val = u[32 + c] - u[c];
      else if (k == TPTS - 1) val = u[(size_t)(TPTS - 1) * 32 + c] - u[(size_t)(TPTS - 2) * 32 + c];
      else val = 0.5f * (u[(size_t)(k + 1) * 32 + c] - u[(size_t)(k - 1) * 32 + c]);
    }
  }
  Wtap[(size_t)n * 128 + tid] = val;
}

// Top-level (stride-1024) starts; ||R^1024|| ~ 6e-5 so 2-term series suffices.
__global__ __launch_bounds__(256) void top_scan(const float* __restrict__ V2, const float* __restrict__ x0,
                                                const float* __restrict__ R1024, float* __restrict__ X2) {
  int k = blockIdx.x, i = threadIdx.x;
  if (k == 0) { X2[i] = x0[i]; return; }
  __shared__ float prev[256];
  const float* pv = (k == 1) ? x0 : (V2 + (size_t)(k - 2) * 256);
  prev[i] = pv[i];
  __syncthreads();
  float acc = V2[(size_t)(k - 1) * 256 + i];
  const float* rr = R1024 + (size_t)i * 256;
  for (int j = 0; j < 256; j += 4) {
    float4 rv = *(const float4*)(rr + j);
    acc += rv.x * prev[j] + rv.y * prev[j + 1] + rv.z * prev[j + 2] + rv.w * prev[j + 3];
  }
  X2[(size_t)k * 256 + i] = acc;
}

// y = x @ C^T + u @ D^T
__global__ __launch_bounds__(256) void y_kernel(const float* __restrict__ x, const float* __restrict__ u,
                                                const float* __restrict__ Cm, const float* __restrict__ Dm,
                                                float* __restrict__ y) {
  __shared__ float Cs[32][260];
  __shared__ float Ds[32][32];
  __shared__ float xs[8][256];
  __shared__ float us[8][32];
  int tid = threadIdx.x;
  for (int k = tid; k < 8192; k += 256) Cs[k >> 8][k & 255] = Cm[k];
  for (int k = tid; k < 1024; k += 256) Ds[k >> 5][k & 31] = Dm[k];
  int o = tid & 31, rr = tid >> 5;
  int n0 = blockIdx.x * 64;
  for (int g = 0; g < 8; g++) {
    int nb = n0 + g * 8;
    __syncthreads();
    for (int k = tid; k < 2048; k += 256)
      xs[k >> 8][k & 255] = x[(size_t)(nb + (k >> 8)) * 256 + (k & 255)];
    for (int k = tid; k < 256; k += 256)
      us[k >> 5][k & 31] = u[(size_t)(nb + (k >> 5)) * 32 + (k & 31)];
    __syncthreads();
    float acc = 0.f;
    for (int i = 0; i < 256; i += 4) {
      float4 cv = *(const float4*)&Cs[o][i];
      float4 xv = *(const float4*)&xs[rr][i];
      acc += cv.x * xv.x + cv.y * xv.y + cv.z * xv.z + cv.w * xv.w;
    }
#pragma unroll
    for (int c = 0; c < 32; c += 4) {
      float4 dv = *(const float4*)&Ds[o][c];
      float4 uv = *(const float4*)&us[rr][c];
      acc += dv.x * uv.x + dv.y * uv.y + dv.z * uv.z + dv.w * uv.w;
    }
    y[(size_t)(nb + rr) * 32 + o] = acc;
  }
}

extern "C" void kernel_launch(void* const* d_in, const int* in_sizes, int n_in,
                              void* d_out, int out_size, void* d_ws, size_t ws_size,
                              hipStream_t stream) {
  const float* u  = (const float*)d_in[1];
  const float* x0 = (const float*)d_in[2];
  const float* A  = (const float*)d_in[3];
  const float* Bm = (const float*)d_in[4];
  const float* Cm = (const float*)d_in[5];
  const float* Dm = (const float*)d_in[6];
  float* xout = (float*)d_out;                       // [32768][256]
  float* yout = xout + (size_t)TPTS * 256;           // [32768][32]

  char* wsb = (char*)d_ws;
  size_t off = 0;
  auto alloc = [&](size_t bytes) -> void* {
    void* p = (void*)(wsb + off);
    off = (off + bytes + 255) & ~(size_t)255;
    return p;
  };
  float*    Rfp    = (float*)alloc(65536 * 4);
  ushort_t* Rh     = (ushort_t*)alloc(65536 * 2);
  ushort_t* Rl     = (ushort_t*)alloc(65536 * 2);
  float*    R32fp  = (float*)alloc(65536 * 4);
  ushort_t* R32h   = (ushort_t*)alloc(65536 * 2);
  ushort_t* R32l   = (ushort_t*)alloc(65536 * 2);
  float*    RKfp   = (float*)alloc(65536 * 4);       // R^1024
  ushort_t* RKh    = (ushort_t*)alloc(65536 * 2);
  ushort_t* RKl    = (ushort_t*)alloc(65536 * 2);
  float*    ATm    = (float*)alloc(65536 * 4);
  float*    FcatT  = (float*)alloc(128 * 256 * 4);
  float*    Wtap   = (float*)alloc((size_t)TPTS * 128 * 4);
  float*    V0     = (float*)alloc((size_t)TPTS * 256 * 4);
  float*    V1     = (float*)alloc(1024 * 256 * 4);
  float*    V2     = (float*)alloc(32 * 256 * 4);
  float*    X2     = (float*)alloc(32 * 256 * 4);
  float*    X1     = (float*)alloc(1024 * 256 * 4);
  (void)ws_size; (void)in_sizes; (void)n_in; (void)out_size;

  // 1. A^T, unit responses -> R (fp32 + hi/lo split) and FcatT
  transpose_at<<<dim3(16), dim3(256), 0, stream>>>(A, ATm);
  unit_resp<<<dim3(96), dim3(1024), 0, stream>>>(ATm, Bm, Rfp, Rh, Rl, FcatT);

  // 2. R^32 = 32 chained applications of R on unit columns; R^1024 likewise on R^32
  chain_mfma<0><<<dim3(16), dim3(512), 0, stream>>>(Rh, Rl, nullptr, nullptr, R32fp, R32h, R32l);
  chain_mfma<0><<<dim3(16), dim3(512), 0, stream>>>(R32h, R32l, nullptr, nullptr, RKfp, RKh, RKl);

  // 3. Hermite taps and per-step drive v_n (fp32 GEMM, K=128)
  build_wtap<<<dim3(TPTS), dim3(128), 0, stream>>>(u, Wtap);
  gemm128<<<dim3(256, 2), dim3(256), 0, stream>>>(Wtap, FcatT, V0, TPTS, 128);

  // 4. reduces: V1[j] = sum_i R^(31-i) v_{32j+i};  V2[k] = sum_j R32^(31-j) V1[32k+j]
  chain_mfma<1><<<dim3(64), dim3(512), 0, stream>>>(Rh, Rl, nullptr, V0, V1, nullptr, nullptr);
  chain_mfma<1><<<dim3(2), dim3(512), 0, stream>>>(R32h, R32l, nullptr, V1, V2, nullptr, nullptr);

  // 5. top starts, then expand down two levels
  top_scan<<<dim3(32), dim3(256), 0, stream>>>(V2, x0, RKfp, X2);
  chain_mfma<2><<<dim3(2), dim3(512), 0, stream>>>(R32h, R32l, X2, V1, X1, nullptr, nullptr);
  chain_mfma<2><<<dim3(64), dim3(512), 0, stream>>>(Rh, Rl, X1, V0, xout, nullptr, nullptr);

  // 6. outputs y
  y_kernel<<<dim3(512), dim3(256), 0, stream>>>(xout, u, Cm, Dm, yout);
}

// Round 3
// 457.807 us; speedup vs baseline: 1.1404x; 1.0491x over previous
//
#include <hip/hip_runtime.h>

// Flow_49160195670664: Dopri5 fixed-step integration of dx/dt = A x + B u(t),
// T=32768, N=256, NI=NO=32, dt=1, Hermite-interpolated stage inputs.
// Linear system => x_{n+1} = R x_n + v_n with constant R; 2-level blocked
// parallel scan (32 x 32 x 32). Sequential-chain parts run on MFMA with
// bf16 hi/lo split (x*R ~ xh*Rh + xl*Rh + xh*Rl, fp32 accumulate).

#define TPTS 32768

typedef __attribute__((ext_vector_type(8))) short short8;
typedef __attribute__((ext_vector_type(4))) float float4v;
typedef unsigned short ushort_t;

__device__ __forceinline__ ushort_t bf16_hi(float f) {
  unsigned u = __builtin_bit_cast(unsigned, f);
  unsigned r = (u + 0x7FFFu + ((u >> 16) & 1u)) >> 16;
  return (ushort_t)r;
}
__device__ __forceinline__ float bf16_f(ushort_t h) {
  unsigned u = ((unsigned)h) << 16;
  return __builtin_bit_cast(float, u);
}

// ---------------------------------------------------------------------------
// MFMA chain kernel v3. 1024 thr = 16 waves; wave w owns output cols
// [16w,16w+16) as ONE N-tile of mfma_f32_16x16x32_bf16; 16 chains = M-dim.
// v2 (8 waves x 2 tiles) needed 128 VGPRs of R^T frags alone and spilled them
// to scratch at VGPR_Count=120 -> every step re-read 512B/thread through L2
// (~1.9us/step, MfmaUtil 7.5%). One tile per wave = 64 frag VGPRs: resident.
// 4 waves/SIMD instead of 2 also doubles latency hiding.
// R^T B-frags live in VGPRs, residency FORCED by per-value "+v" asm pins inside
// the loop (a rw-operand's output must persist across iterations).
// 3 independent accumulators: dependent-MFMA depth 8.
// V-drive is per-lane register-prefetched one step ahead (no vbuf LDS/barrier).
// MODE 2 stores go through a 5-slot LDS ring, flushed 4 rows per 4 steps just
// after a barrier so the global-store drain overlaps the next step's MFMAs.
// MODE 0: power  (32 steps, x0 = I cols; Out=R^32 row-major fp32 + h/l split)
// MODE 1: reduce (31 steps, x0 = V row0, drive rows 1..31; Out[chain] = final x)
// MODE 2: expand (31 steps, x0 = X0, drive rows 0..30; Out rows chain*32+j)
template <int MODE>
__global__ __launch_bounds__(1024, 4) void chain_mfma(const ushort_t* Mh, const ushort_t* Ml,
                                                      const float* X0, const float* V,
                                                      float* Out, ushort_t* OutH, ushort_t* OutL) {
  constexpr int STEPS = (MODE == 0) ? 32 : 31;
  constexpr int HSLOTS = (MODE == 2) ? 5 : 1;
  int blk = blockIdx.x, t = threadIdx.x;
  int w = t >> 6, l = t & 63;   // w 0..15
  int q = l >> 4, c16 = l & 15;
  int n0 = w * 16;
  // B-frags: B[k][n] = R[n][k]; lane holds B[kt*32+q*8+j][n0+c16], j=0..7
  short8 bh[8], bl[8];
#pragma unroll
  for (int kt = 0; kt < 8; kt++) {
    size_t offs = (size_t)(n0 + c16) * 256 + kt * 32 + q * 8;
    bh[kt] = *(const short8*)(Mh + offs);
    bl[kt] = *(const short8*)(Ml + offs);
  }
  __shared__ __attribute__((aligned(16))) ushort_t xh[2][32][16][8];  // [buf][k>>3][chain][k&7]
  __shared__ __attribute__((aligned(16))) ushort_t xl[2][32][16][8];
  __shared__ float hist[HSLOTS][16][256];
  // initial x (and row-0 store for MODE 2): 1024 float4, one per thread
  {
    int e = t;
    int c = e >> 6, qq = (e & 63) * 4;
    int cg = blk * 16 + c;
    float4 v4;
    if (MODE == 0) {
      v4 = make_float4(qq == cg ? 1.f : 0.f, qq + 1 == cg ? 1.f : 0.f,
                       qq + 2 == cg ? 1.f : 0.f, qq + 3 == cg ? 1.f : 0.f);
    } else if (MODE == 1) {
      v4 = *(const float4*)(V + (size_t)cg * 32 * 256 + qq);
    } else {
      v4 = *(const float4*)(X0 + (size_t)cg * 256 + qq);
      *(float4*)(Out + ((size_t)cg * 32) * 256 + qq) = v4;
    }
    float vals[4] = {v4.x, v4.y, v4.z, v4.w};
#pragma unroll
    for (int i = 0; i < 4; i++) {
      int n = qq + i;
      ushort_t h = bf16_hi(vals[i]);
      xh[0][n >> 3][c][n & 7] = h;
      xl[0][n >> 3][c][n & 7] = bf16_hi(vals[i] - bf16_f(h));
    }
  }
  // per-lane drive prefetch for step 1 (element r: chain q*4+r, col n0+c16)
  float vnext[4];
  if (MODE != 0) {
#pragma unroll
    for (int r = 0; r < 4; r++) {
      int cg = blk * 16 + q * 4 + r;
      int drow = (MODE == 1) ? 1 : 0;
      vnext[r] = V[((size_t)cg * 32 + drow) * 256 + n0 + c16];
    }
  }
  __syncthreads();
  for (int s = 1; s <= STEPS; s++) {
    int cur = (s - 1) & 1, nxt = s & 1;
    // MODE 2: flush rows s-4..s-1 (slots row%5) — reads race-free vs writes (mod-5 disjoint)
    if (MODE == 2 && s >= 5 && ((s - 1) & 3) == 0) {
      int rbase = s - 4;
      for (int e = t; e < 4096; e += 1024) {
        int slot = e >> 10;
        int rem = e & 1023;
        int c = rem >> 6, qq = (rem & 63) * 4;
        int row = rbase + slot;
        int cg = blk * 16 + c;
        *(float4*)(Out + ((size_t)cg * 32 + row) * 256 + qq) = *(const float4*)&hist[row % 5][c][qq];
      }
    }
    // drive: consume prefetched, issue next step's loads (hidden under MFMAs)
    float vc[4];
    if (MODE != 0) {
#pragma unroll
      for (int i2 = 0; i2 < 4; i2++) vc[i2] = vnext[i2];
      if (s < STEPS) {
        int drow = (MODE == 1) ? (s + 1) : s;
#pragma unroll
        for (int r = 0; r < 4; r++)
          vnext[r] = V[((size_t)(blk * 16 + q * 4 + r) * 32 + drow) * 256 + n0 + c16];
      }
    }
    // pin frags: rw asm operand => value must live in VGPRs, reload illegal
#pragma unroll
    for (int kt = 0; kt < 8; kt++) {
      asm volatile("" : "+v"(bh[kt]));
      asm volatile("" : "+v"(bl[kt]));
    }
    float4v aH = {0.f, 0.f, 0.f, 0.f};
    float4v aL = {0.f, 0.f, 0.f, 0.f};
    float4v aC = {0.f, 0.f, 0.f, 0.f};
#pragma unroll
    for (int kt = 0; kt < 8; kt++) {
      short8 ah = *(const short8*)&xh[cur][kt * 4 + q][c16][0];
      short8 al = *(const short8*)&xl[cur][kt * 4 + q][c16][0];
      aH = __builtin_amdgcn_mfma_f32_16x16x32_bf16(ah, bh[kt], aH, 0, 0, 0);
      aL = __builtin_amdgcn_mfma_f32_16x16x32_bf16(al, bh[kt], aL, 0, 0, 0);
      aC = __builtin_amdgcn_mfma_f32_16x16x32_bf16(ah, bl[kt], aC, 0, 0, 0);
    }
    // epilogue: C/D layout chain=(q*4+r), col=c16 (m89-verified)
#pragma unroll
    for (int r = 0; r < 4; r++) {
      int c = q * 4 + r;
      int n = n0 + c16;
      float val = aH[r] + aL[r] + aC[r];
      if (MODE != 0) val += vc[r];
      int cg = blk * 16 + c;
      if (MODE == 2) hist[s % 5][c][n] = val;
      if (MODE == 1 && s == STEPS) Out[(size_t)cg * 256 + n] = val;
      if (MODE == 0 && s == STEPS) {
        ushort_t h2 = bf16_hi(val);
        Out[(size_t)n * 256 + cg] = val;
        OutH[(size_t)n * 256 + cg] = h2;
        OutL[(size_t)n * 256 + cg] = bf16_hi(val - bf16_f(h2));
      }
      ushort_t h = bf16_hi(val);
      xh[nxt][n >> 3][c][n & 7] = h;
      xl[nxt][n >> 3][c][n & 7] = bf16_hi(val - bf16_f(h));
    }
    __syncthreads();
  }
  if (MODE == 2) {   // final rows 29,30,31
    for (int e = t; e < 3072; e += 1024) {
      int slot = e >> 10;
      int rem = e & 1023;
      int c = rem >> 6, qq = (rem & 63) * 4;
      int row = 29 + slot;
      int cg = blk * 16 + c;
      *(float4*)(Out + ((size_t)cg * 32 + row) * 256 + qq) = *(const float4*)&hist[row % 5][c][qq];
    }
  }
}

// ---------------------------------------------------------------------------
// fp32 GEMM for the drive: C[M][256] = A[M][K] @ B[K][256], BM=BN=128, BK=8.
__global__ __launch_bounds__(256) void gemm128(const float* __restrict__ A, const float* __restrict__ B,
                                               float* __restrict__ C, int M, int K) {
  int m0 = blockIdx.x * 128, n0 = blockIdx.y * 128;
  __shared__ float As[8][128];
  __shared__ float Bs[8][128];
  int tid = threadIdx.x;
  int am = tid >> 1, akc = (tid & 1) * 4;
  int bk = tid >> 5, bn = (tid & 31) * 4;
  int ty = tid >> 4, tx = tid & 15;
  float acc[8][8] = {{0.f}};
  for (int kt = 0; kt < K; kt += 8) {
    float4 av = make_float4(0.f, 0.f, 0.f, 0.f);
    if (m0 + am < M) av = *(const float4*)(A + (size_t)(m0 + am) * K + kt + akc);
    float4 bv = *(const float4*)(B + (size_t)(kt + bk) * 256 + n0 + bn);
    __syncthreads();
    As[akc + 0][am] = av.x;
    As[akc + 1][am] = av.y;
    As[akc + 2][am] = av.z;
    As[akc + 3][am] = av.w;
    *(float4*)&Bs[bk][bn] = bv;
    __syncthreads();
#pragma unroll
    for (int kk = 0; kk < 8; kk++) {
      float4 a0 = *(const float4*)&As[kk][ty * 8];
      float4 a1 = *(const float4*)&As[kk][ty * 8 + 4];
      float4 b0 = *(const float4*)&Bs[kk][tx * 8];
      float4 b1 = *(const float4*)&Bs[kk][tx * 8 + 4];
      float ar[8] = {a0.x, a0.y, a0.z, a0.w, a1.x, a1.y, a1.z, a1.w};
      float br[8] = {b0.x, b0.y, b0.z, b0.w, b1.x, b1.y, b1.z, b1.w};
#pragma unroll
      for (int i = 0; i < 8; i++)
#pragma unroll
        for (int j = 0; j < 8; j++) acc[i][j] += ar[i] * br[j];
    }
  }
#pragma unroll
  for (int i = 0; i < 8; i++) {
    int row = m0 + ty * 8 + i;
    if (row < M) {
      *(float4*)&C[(size_t)row * 256 + n0 + tx * 8] = make_float4(acc[i][0], acc[i][1], acc[i][2], acc[i][3]);
      *(float4*)&C[(size_t)row * 256 + n0 + tx * 8 + 4] = make_float4(acc[i][4], acc[i][5], acc[i][6], acc[i][7]);
    }
  }
}

// AT = A^T (256x256)
__global__ __launch_bounds__(256) void transpose_at(const float* __restrict__ A, float* __restrict__ AT) {
  __shared__ float tile[64][65];
  int bx = blockIdx.x & 3, by = blockIdx.x >> 2;
  int r0 = by * 64, c0 = bx * 64;
  int t = threadIdx.x;
  int lr = t >> 4, lc = (t & 15) * 4;
  for (int rr = lr; rr < 64; rr += 16) {
    float4 v = *(const float4*)(A + (size_t)(r0 + rr) * 256 + c0 + lc);
    tile[rr][lc + 0] = v.x; tile[rr][lc + 1] = v.y; tile[rr][lc + 2] = v.z; tile[rr][lc + 3] = v.w;
  }
  __syncthreads();
  for (int rr = lr; rr < 64; rr += 16) {
    float4 v = make_float4(tile[lc + 0][rr], tile[lc + 1][rr], tile[lc + 2][rr], tile[lc + 3][rr]);
    *(float4*)(AT + (size_t)(c0 + rr) * 256 + r0 + lc) = v;
  }
}

// Unit responses through one Dopri5 step: cols 0..255 -> R fp32 + bf16 hi/lo
// split; cols 256..383 -> Hermite-folded tap matrices transposed into FcatT.
// v2: 1024 threads = 4 j-groups x 256 rows; 4-way split-K with LDS reduce.
__global__ __launch_bounds__(1024) void unit_resp(const float* __restrict__ AT,
                                                  const float* __restrict__ Bm,
                                                  float* __restrict__ Rout,
                                                  ushort_t* __restrict__ Rh,
                                                  ushort_t* __restrict__ Rl,
                                                  float* __restrict__ FcatT) {
  int blk = blockIdx.x;
  int tid = threadIdx.x;
  int jg = tid >> 8;   // j-group 0..3, also the owned column index cc
  int i = tid & 255;   // output row
  int cc = jg;
  int col = blk * 4 + cc;

  __shared__ float xs4[256][4];
  __shared__ float4 part[4][256];

  const float AA[6][5] = {
      {0.f, 0.f, 0.f, 0.f, 0.f},
      {0.2f, 0.f, 0.f, 0.f, 0.f},
      {3.f / 40.f, 9.f / 40.f, 0.f, 0.f, 0.f},
      {44.f / 45.f, -56.f / 15.f, 32.f / 9.f, 0.f, 0.f},
      {19372.f / 6561.f, -25360.f / 2187.f, 64448.f / 6561.f, -212.f / 729.f, 0.f},
      {9017.f / 3168.f, -355.f / 33.f, 46732.f / 5247.f, 49.f / 176.f, -5103.f / 18656.f}};
  const float BB[6] = {35.f / 384.f, 0.f, 500.f / 1113.f, 125.f / 192.f, -2187.f / 6784.f, 11.f / 84.f};
  const float sv[6] = {0.f, 0.2f, 0.3f, 0.8f, 8.f / 9.f, 1.f};
  float Hm[6][4];
#pragma unroll
  for (int s = 0; s < 6; s++) {
    float ss = sv[s], s2 = ss * ss, s3 = s2 * ss;
    Hm[s][0] = 2.f * s3 - 3.f * s2 + 1.f;
    Hm[s][1] = s3 - 2.f * s2 + ss;
    Hm[s][2] = -2.f * s3 + 3.f * s2;
    Hm[s][3] = s3 - s2;
  }

  // owned-column metadata
  int isF, tt;
  float brow, xc;
  if (col < 256) {
    isF = 0; tt = 0; brow = 0.f;
    xc = (i == col) ? 1.f : 0.f;
  } else {
    isF = 1; xc = 0.f;
    int f = col - 256;
    tt = f >> 5;
    brow = Bm[i * 32 + (f & 31)];
  }
  float bh[6];
#pragma unroll
  for (int s = 0; s < 6; s++) {
    float hv = (tt == 0) ? Hm[s][0] : ((tt == 1) ? Hm[s][1] : ((tt == 2) ? Hm[s][2] : Hm[s][3]));
    bh[s] = isF ? hv * brow : 0.f;
  }

  float kreg[6];
#pragma unroll
  for (int s = 0; s < 6; s++) kreg[s] = 0.f;

  int j0 = jg * 64;
#pragma unroll 1
  for (int s = 0; s < 6; s++) {
    // stage input for the owned column (register k's -> LDS)
    float xsv = xc;
#pragma unroll
    for (int j = 0; j < 5; j++)
      if (j < s) xsv += AA[s][j] * kreg[j];
    xs4[i][cc] = xsv;
    __syncthreads();
    // partial matvec over this thread's 64-row j-slice (4 cols per load)
    float acx = 0.f, acy = 0.f, acz = 0.f, acw = 0.f;
#pragma unroll 8
    for (int jj = 0; jj < 64; jj++) {
      int j = j0 + jj;
      float a = AT[(size_t)j * 256 + i];
      float4 xv = *(const float4*)xs4[j];
      acx += a * xv.x;
      acy += a * xv.y;
      acz += a * xv.z;
      acw += a * xv.w;
    }
    part[jg][i] = make_float4(acx, acy, acz, acw);
    __syncthreads();
    // owner reduces the 4 partials for its column
    float k = bh[s];
#pragma unroll
    for (int g = 0; g < 4; g++) {
      const float* p = (const float*)&part[g][i];
      k += p[cc];
    }
    kreg[s] = k;
  }

  float o = xc;
#pragma unroll
  for (int s = 0; s < 6; s++) o += BB[s] * kreg[s];
  if (!isF) {
    Rout[(size_t)i * 256 + col] = o;
    ushort_t h = bf16_hi(o);
    Rh[(size_t)i * 256 + col] = h;
    Rl[(size_t)i * 256 + col] = bf16_hi(o - bf16_f(h));
  } else {
    FcatT[(size_t)(col - 256) * 256 + i] = o;
  }
}

// Wtap[n][tap] = {u_n, m_n, u_{n+1}, m_{n+1}} taps; row 32767 = 0 (pad).
__global__ __launch_bounds__(128) void build_wtap(const float* __restrict__ u, float* __restrict__ Wtap) {
  int n = blockIdx.x;
  int tid = threadIdx.x;
  int t = tid >> 5, c = tid & 31;
  float val = 0.f;
  if (n < TPTS - 1) {
    if (t == 0) val = u[(size_t)n * 32 + c];
    else if (t == 2) val = u[(size_t)(n + 1) * 32 + c];
    else {
      int k = (t == 1) ? n : n + 1;
      if (k == 0) val = u[32 + c] - u[c];
      else if (k == TPTS - 1) val = u[(size_t)(TPTS - 1) * 32 + c] - u[(size_t)(TPTS - 2) * 32 + c];
      else val = 0.5f * (u[(size_t)(k + 1) * 32 + c] - u[(size_t)(k - 1) * 32 + c]);
    }
  }
  Wtap[(size_t)n * 128 + tid] = val;
}

// Top-level (stride-1024) starts; ||R^1024|| ~ 6e-5 so 2-term series suffices.
__global__ __launch_bounds__(256) void top_scan(const float* __restrict__ V2, const float* __restrict__ x0,
                                                const float* __restrict__ R1024, float* __restrict__ X2) {
  int k = blockIdx.x, i = threadIdx.x;
  if (k == 0) { X2[i] = x0[i]; return; }
  __shared__ float prev[256];
  const float* pv = (k == 1) ? x0 : (V2 + (size_t)(k - 2) * 256);
  prev[i] = pv[i];
  __syncthreads();
  float acc = V2[(size_t)(k - 1) * 256 + i];
  const float* rr = R1024 + (size_t)i * 256;
  for (int j = 0; j < 256; j += 4) {
    float4 rv = *(const float4*)(rr + j);
    acc += rv.x * prev[j] + rv.y * prev[j + 1] + rv.z * prev[j + 2] + rv.w * prev[j + 3];
  }
  X2[(size_t)k * 256 + i] = acc;
}

// y = x @ C^T + u @ D^T
__global__ __launch_bounds__(256) void y_kernel(const float* __restrict__ x, const float* __restrict__ u,
                                                const float* __restrict__ Cm, const float* __restrict__ Dm,
                                                float* __restrict__ y) {
  __shared__ float Cs[32][260];
  __shared__ float Ds[32][32];
  __shared__ float xs[8][256];
  __shared__ float us[8][32];
  int tid = threadIdx.x;
  for (int k = tid; k < 8192; k += 256) Cs[k >> 8][k & 255] = Cm[k];
  for (int k = tid; k < 1024; k += 256) Ds[k >> 5][k & 31] = Dm[k];
  int o = tid & 31, rr = tid >> 5;
  int n0 = blockIdx.x * 64;
  for (int g = 0; g < 8; g++) {
    int nb = n0 + g * 8;
    __syncthreads();
    for (int k = tid; k < 2048; k += 256)
      xs[k >> 8][k & 255] = x[(size_t)(nb + (k >> 8)) * 256 + (k & 255)];
    for (int k = tid; k < 256; k += 256)
      us[k >> 5][k & 31] = u[(size_t)(nb + (k >> 5)) * 32 + (k & 31)];
    __syncthreads();
    float acc = 0.f;
    for (int i = 0; i < 256; i += 4) {
      float4 cv = *(const float4*)&Cs[o][i];
      float4 xv = *(const float4*)&xs[rr][i];
      acc += cv.x * xv.x + cv.y * xv.y + cv.z * xv.z + cv.w * xv.w;
    }
#pragma unroll
    for (int c = 0; c < 32; c += 4) {
      float4 dv = *(const float4*)&Ds[o][c];
      float4 uv = *(const float4*)&us[rr][c];
      acc += dv.x * uv.x + dv.y * uv.y + dv.z * uv.z + dv.w * uv.w;
    }
    y[(size_t)(nb + rr) * 32 + o] = acc;
  }
}

extern "C" void kernel_launch(void* const* d_in, const int* in_sizes, int n_in,
                              void* d_out, int out_size, void* d_ws, size_t ws_size,
                              hipStream_t stream) {
  const float* u  = (const float*)d_in[1];
  const float* x0 = (const float*)d_in[2];
  const float* A  = (const float*)d_in[3];
  const float* Bm = (const float*)d_in[4];
  const float* Cm = (const float*)d_in[5];
  const float* Dm = (const float*)d_in[6];
  float* xout = (float*)d_out;                       // [32768][256]
  float* yout = xout + (size_t)TPTS * 256;           // [32768][32]

  char* wsb = (char*)d_ws;
  size_t off = 0;
  auto alloc = [&](size_t bytes) -> void* {
    void* p = (void*)(wsb + off);
    off = (off + bytes + 255) & ~(size_t)255;
    return p;
  };
  float*    Rfp    = (float*)alloc(65536 * 4);
  ushort_t* Rh     = (ushort_t*)alloc(65536 * 2);
  ushort_t* Rl     = (ushort_t*)alloc(65536 * 2);
  float*    R32fp  = (float*)alloc(65536 * 4);
  ushort_t* R32h   = (ushort_t*)alloc(65536 * 2);
  ushort_t* R32l   = (ushort_t*)alloc(65536 * 2);
  float*    RKfp   = (float*)alloc(65536 * 4);       // R^1024
  ushort_t* RKh    = (ushort_t*)alloc(65536 * 2);
  ushort_t* RKl    = (ushort_t*)alloc(65536 * 2);
  float*    ATm    = (float*)alloc(65536 * 4);
  float*    FcatT  = (float*)alloc(128 * 256 * 4);
  float*    Wtap   = (float*)alloc((size_t)TPTS * 128 * 4);
  float*    V0     = (float*)alloc((size_t)TPTS * 256 * 4);
  float*    V1     = (float*)alloc(1024 * 256 * 4);
  float*    V2     = (float*)alloc(32 * 256 * 4);
  float*    X2     = (float*)alloc(32 * 256 * 4);
  float*    X1     = (float*)alloc(1024 * 256 * 4);
  (void)ws_size; (void)in_sizes; (void)n_in; (void)out_size;

  // 1. A^T, unit responses -> R (fp32 + hi/lo split) and FcatT
  transpose_at<<<dim3(16), dim3(256), 0, stream>>>(A, ATm);
  unit_resp<<<dim3(96), dim3(1024), 0, stream>>>(ATm, Bm, Rfp, Rh, Rl, FcatT);

  // 2. R^32 = 32 chained applications of R on unit columns; R^1024 likewise on R^32
  chain_mfma<0><<<dim3(16), dim3(1024), 0, stream>>>(Rh, Rl, nullptr, nullptr, R32fp, R32h, R32l);
  chain_mfma<0><<<dim3(16), dim3(1024), 0, stream>>>(R32h, R32l, nullptr, nullptr, RKfp, RKh, RKl);

  // 3. Hermite taps and per-step drive v_n (fp32 GEMM, K=128)
  build_wtap<<<dim3(TPTS), dim3(128), 0, stream>>>(u, Wtap);
  gemm128<<<dim3(256, 2), dim3(256), 0, stream>>>(Wtap, FcatT, V0, TPTS, 128);

  // 4. reduces: V1[j] = sum_i R^(31-i) v_{32j+i};  V2[k] = sum_j R32^(31-j) V1[32k+j]
  chain_mfma<1><<<dim3(64), dim3(1024), 0, stream>>>(Rh, Rl, nullptr, V0, V1, nullptr, nullptr);
  chain_mfma<1><<<dim3(2), dim3(1024), 0, stream>>>(R32h, R32l, nullptr, V1, V2, nullptr, nullptr);

  // 5. top starts, then expand down two levels
  top_scan<<<dim3(32), dim3(256), 0, stream>>>(V2, x0, RKfp, X2);
  chain_mfma<2><<<dim3(2), dim3(1024), 0, stream>>>(R32h, R32l, X2, V1, X1, nullptr, nullptr);
  chain_mfma<2><<<dim3(64), dim3(1024), 0, stream>>>(Rh, Rl, X1, V0, xout, nullptr, nullptr);

  // 6. outputs y
  y_kernel<<<dim3(512), dim3(256), 0, stream>>>(xout, u, Cm, Dm, yout);
}

// Round 5
// 363.327 us; speedup vs baseline: 1.4369x; 1.2600x over previous
//
#include <hip/hip_runtime.h>

// Flow_49160195670664: Dopri5 fixed-step integration of dx/dt = A x + B u(t),
// T=32768, N=256, NI=NO=32, dt=1, Hermite-interpolated stage inputs.
// Linear system => x_{n+1} = R x_n + v_n with constant R.
// v4: 4-level blocked parallel scan 8 x 8 x 8 x 64 (was 32x32x32).
// Rationale (r3 counters): per-step time of chain_mfma is ~1.75us regardless
// of block count (64-blk and 2-blk dispatches both ~54us) -> sequential-step
// latency floor. 3-level tree paid 188 steps (~324us); 4-level pays 66 steps
// (powers 8+8+8, reduces 7+7+7, expands 7+7+7) and puts 256 blocks on the
// finest level. Top level: 64 starts with R^512, 3-term truncated recurrence
// (error ~||R^1536|| ~ 5e-7; exact for k<=2).

#define TPTS 32768

typedef __attribute__((ext_vector_type(8))) short short8;
typedef __attribute__((ext_vector_type(4))) float float4v;
typedef unsigned short ushort_t;

__device__ __forceinline__ ushort_t bf16_hi(float f) {
  unsigned u = __builtin_bit_cast(unsigned, f);
  unsigned r = (u + 0x7FFFu + ((u >> 16) & 1u)) >> 16;
  return (ushort_t)r;
}
__device__ __forceinline__ float bf16_f(ushort_t h) {
  unsigned u = ((unsigned)h) << 16;
  return __builtin_bit_cast(float, u);
}

// ---------------------------------------------------------------------------
// MFMA chain kernel v4. 1024 thr = 16 waves; wave w owns output cols
// [16w,16w+16) as ONE N-tile of mfma_f32_16x16x32_bf16; 16 chains = M-dim.
// bf16 hi/lo split (x*R ~ xh*Rh + xl*Rh + xh*Rl, fp32 accumulate), 3
// independent accumulators. V-drive register-prefetched one step ahead.
// CLEN = rows per chain (8 for scan levels). STEPS = CLEN (MODE 0) or CLEN-1.
// MODE 0: power  (CLEN steps, x0 = I cols; Out = M^CLEN row-major fp32 + h/l)
// MODE 1: reduce (x0 = V row0 of chain, drive rows 1..CLEN-1; Out[chain]=final)
// MODE 2: expand (x0 = X0[chain], drive rows 0..CLEN-2; Out rows chain*CLEN+j)
// MODE 2 stores go through a 5-slot LDS ring: rows 1..4(+) flushed in groups
// of 4 right after a barrier; final 3 rows (STEPS-2..STEPS) at the end.
template <int MODE, int CLEN>
__global__ __launch_bounds__(1024, 4) void chain_mfma(const ushort_t* Mh, const ushort_t* Ml,
                                                      const float* X0, const float* V,
                                                      float* Out, ushort_t* OutH, ushort_t* OutL) {
  constexpr int STEPS = (MODE == 0) ? CLEN : CLEN - 1;
  constexpr int HSLOTS = (MODE == 2) ? 5 : 1;
  int blk = blockIdx.x, t = threadIdx.x;
  int w = t >> 6, l = t & 63;   // w 0..15
  int q = l >> 4, c16 = l & 15;
  int n0 = w * 16;
  // B-frags: B[k][n] = M[n][k]; lane holds B[kt*32+q*8+j][n0+c16], j=0..7
  short8 bh[8], bl[8];
#pragma unroll
  for (int kt = 0; kt < 8; kt++) {
    size_t offs = (size_t)(n0 + c16) * 256 + kt * 32 + q * 8;
    bh[kt] = *(const short8*)(Mh + offs);
    bl[kt] = *(const short8*)(Ml + offs);
  }
  __shared__ __attribute__((aligned(16))) ushort_t xh[2][32][16][8];  // [buf][k>>3][chain][k&7]
  __shared__ __attribute__((aligned(16))) ushort_t xl[2][32][16][8];
  __shared__ float hist[HSLOTS][16][256];
  // initial x (and row-0 store for MODE 2): 1024 float4, one per thread
  {
    int e = t;
    int c = e >> 6, qq = (e & 63) * 4;
    int cg = blk * 16 + c;
    float4 v4;
    if (MODE == 0) {
      v4 = make_float4(qq == cg ? 1.f : 0.f, qq + 1 == cg ? 1.f : 0.f,
                       qq + 2 == cg ? 1.f : 0.f, qq + 3 == cg ? 1.f : 0.f);
    } else if (MODE == 1) {
      v4 = *(const float4*)(V + (size_t)cg * CLEN * 256 + qq);
    } else {
      v4 = *(const float4*)(X0 + (size_t)cg * 256 + qq);
      *(float4*)(Out + ((size_t)cg * CLEN) * 256 + qq) = v4;
    }
    float vals[4] = {v4.x, v4.y, v4.z, v4.w};
#pragma unroll
    for (int i = 0; i < 4; i++) {
      int n = qq + i;
      ushort_t h = bf16_hi(vals[i]);
      xh[0][n >> 3][c][n & 7] = h;
      xl[0][n >> 3][c][n & 7] = bf16_hi(vals[i] - bf16_f(h));
    }
  }
  // per-lane drive prefetch for step 1 (element r: chain q*4+r, col n0+c16)
  float vnext[4];
  if (MODE != 0) {
#pragma unroll
    for (int r = 0; r < 4; r++) {
      int cg = blk * 16 + q * 4 + r;
      int drow = (MODE == 1) ? 1 : 0;
      vnext[r] = V[((size_t)cg * CLEN + drow) * 256 + n0 + c16];
    }
  }
  __syncthreads();
  for (int s = 1; s <= STEPS; s++) {
    int cur = (s - 1) & 1, nxt = s & 1;
    // MODE 2: flush rows s-4..s-1 (slots row%5) — reads race-free vs writes (mod-5 disjoint)
    if (MODE == 2 && s >= 5 && ((s - 1) & 3) == 0) {
      int rbase = s - 4;
      for (int e = t; e < 4096; e += 1024) {
        int slot = e >> 10;
        int rem = e & 1023;
        int c = rem >> 6, qq = (rem & 63) * 4;
        int row = rbase + slot;
        int cg = blk * 16 + c;
        *(float4*)(Out + ((size_t)cg * CLEN + row) * 256 + qq) = *(const float4*)&hist[row % 5][c][qq];
      }
    }
    // drive: consume prefetched, issue next step's loads (hidden under MFMAs)
    float vc[4];
    if (MODE != 0) {
#pragma unroll
      for (int i2 = 0; i2 < 4; i2++) vc[i2] = vnext[i2];
      if (s < STEPS) {
        int drow = (MODE == 1) ? (s + 1) : s;
#pragma unroll
        for (int r = 0; r < 4; r++)
          vnext[r] = V[((size_t)(blk * 16 + q * 4 + r) * CLEN + drow) * 256 + n0 + c16];
      }
    }
    // pin frags: rw asm operand => value must live in VGPRs, reload illegal
#pragma unroll
    for (int kt = 0; kt < 8; kt++) {
      asm volatile("" : "+v"(bh[kt]));
      asm volatile("" : "+v"(bl[kt]));
    }
    float4v aH = {0.f, 0.f, 0.f, 0.f};
    float4v aL = {0.f, 0.f, 0.f, 0.f};
    float4v aC = {0.f, 0.f, 0.f, 0.f};
#pragma unroll
    for (int kt = 0; kt < 8; kt++) {
      short8 ah = *(const short8*)&xh[cur][kt * 4 + q][c16][0];
      short8 al = *(const short8*)&xl[cur][kt * 4 + q][c16][0];
      aH = __builtin_amdgcn_mfma_f32_16x16x32_bf16(ah, bh[kt], aH, 0, 0, 0);
      aL = __builtin_amdgcn_mfma_f32_16x16x32_bf16(al, bh[kt], aL, 0, 0, 0);
      aC = __builtin_amdgcn_mfma_f32_16x16x32_bf16(ah, bl[kt], aC, 0, 0, 0);
    }
    // epilogue: C/D layout chain=(q*4+r), col=c16 (m89-verified)
#pragma unroll
    for (int r = 0; r < 4; r++) {
      int c = q * 4 + r;
      int n = n0 + c16;
      float val = aH[r] + aL[r] + aC[r];
      if (MODE != 0) val += vc[r];
      int cg = blk * 16 + c;
      if (MODE == 2) hist[s % 5][c][n] = val;
      if (MODE == 1 && s == STEPS) Out[(size_t)cg * 256 + n] = val;
      if (MODE == 0 && s == STEPS) {
        ushort_t h2 = bf16_hi(val);
        Out[(size_t)n * 256 + cg] = val;
        OutH[(size_t)n * 256 + cg] = h2;
        OutL[(size_t)n * 256 + cg] = bf16_hi(val - bf16_f(h2));
      }
      ushort_t h = bf16_hi(val);
      xh[nxt][n >> 3][c][n & 7] = h;
      xl[nxt][n >> 3][c][n & 7] = bf16_hi(val - bf16_f(h));
    }
    __syncthreads();
  }
  if (MODE == 2) {   // final rows STEPS-2..STEPS
    for (int e = t; e < 3072; e += 1024) {
      int slot = e >> 10;
      int rem = e & 1023;
      int c = rem >> 6, qq = (rem & 63) * 4;
      int row = (STEPS - 2) + slot;
      int cg = blk * 16 + c;
      *(float4*)(Out + ((size_t)cg * CLEN + row) * 256 + qq) = *(const float4*)&hist[row % 5][c][qq];
    }
  }
}

// ---------------------------------------------------------------------------
// fp32 GEMM for the drive: C[M][256] = A[M][K] @ B[K][256], BM=BN=128, BK=8.
__global__ __launch_bounds__(256) void gemm128(const float* __restrict__ A, const float* __restrict__ B,
                                               float* __restrict__ C, int M, int K) {
  int m0 = blockIdx.x * 128, n0 = blockIdx.y * 128;
  __shared__ float As[8][128];
  __shared__ float Bs[8][128];
  int tid = threadIdx.x;
  int am = tid >> 1, akc = (tid & 1) * 4;
  int bk = tid >> 5, bn = (tid & 31) * 4;
  int ty = tid >> 4, tx = tid & 15;
  float acc[8][8] = {{0.f}};
  for (int kt = 0; kt < K; kt += 8) {
    float4 av = make_float4(0.f, 0.f, 0.f, 0.f);
    if (m0 + am < M) av = *(const float4*)(A + (size_t)(m0 + am) * K + kt + akc);
    float4 bv = *(const float4*)(B + (size_t)(kt + bk) * 256 + n0 + bn);
    __syncthreads();
    As[akc + 0][am] = av.x;
    As[akc + 1][am] = av.y;
    As[akc + 2][am] = av.z;
    As[akc + 3][am] = av.w;
    *(float4*)&Bs[bk][bn] = bv;
    __syncthreads();
#pragma unroll
    for (int kk = 0; kk < 8; kk++) {
      float4 a0 = *(const float4*)&As[kk][ty * 8];
      float4 a1 = *(const float4*)&As[kk][ty * 8 + 4];
      float4 b0 = *(const float4*)&Bs[kk][tx * 8];
      float4 b1 = *(const float4*)&Bs[kk][tx * 8 + 4];
      float ar[8] = {a0.x, a0.y, a0.z, a0.w, a1.x, a1.y, a1.z, a1.w};
      float br[8] = {b0.x, b0.y, b0.z, b0.w, b1.x, b1.y, b1.z, b1.w};
#pragma unroll
      for (int i = 0; i < 8; i++)
#pragma unroll
        for (int j = 0; j < 8; j++) acc[i][j] += ar[i] * br[j];
    }
  }
#pragma unroll
  for (int i = 0; i < 8; i++) {
    int row = m0 + ty * 8 + i;
    if (row < M) {
      *(float4*)&C[(size_t)row * 256 + n0 + tx * 8] = make_float4(acc[i][0], acc[i][1], acc[i][2], acc[i][3]);
      *(float4*)&C[(size_t)row * 256 + n0 + tx * 8 + 4] = make_float4(acc[i][4], acc[i][5], acc[i][6], acc[i][7]);
    }
  }
}

// AT = A^T (256x256)
__global__ __launch_bounds__(256) void transpose_at(const float* __restrict__ A, float* __restrict__ AT) {
  __shared__ float tile[64][65];
  int bx = blockIdx.x & 3, by = blockIdx.x >> 2;
  int r0 = by * 64, c0 = bx * 64;
  int t = threadIdx.x;
  int lr = t >> 4, lc = (t & 15) * 4;
  for (int rr = lr; rr < 64; rr += 16) {
    float4 v = *(const float4*)(A + (size_t)(r0 + rr) * 256 + c0 + lc);
    tile[rr][lc + 0] = v.x; tile[rr][lc + 1] = v.y; tile[rr][lc + 2] = v.z; tile[rr][lc + 3] = v.w;
  }
  __syncthreads();
  for (int rr = lr; rr < 64; rr += 16) {
    float4 v = make_float4(tile[lc + 0][rr], tile[lc + 1][rr], tile[lc + 2][rr], tile[lc + 3][rr]);
    *(float4*)(AT + (size_t)(c0 + rr) * 256 + r0 + lc) = v;
  }
}

// Unit responses through one Dopri5 step: cols 0..255 -> R fp32 + bf16 hi/lo
// split; cols 256..383 -> Hermite-folded tap matrices transposed into FcatT.
// v2: 1024 threads = 4 j-groups x 256 rows; 4-way split-K with LDS reduce.
__global__ __launch_bounds__(1024) void unit_resp(const float* __restrict__ AT,
                                                  const float* __restrict__ Bm,
                                                  float* __restrict__ Rout,
                                                  ushort_t* __restrict__ Rh,
                                                  ushort_t* __restrict__ Rl,
                                                  float* __restrict__ FcatT) {
  int blk = blockIdx.x;
  int tid = threadIdx.x;
  int jg = tid >> 8;   // j-group 0..3, also the owned column index cc
  int i = tid & 255;   // output row
  int cc = jg;
  int col = blk * 4 + cc;

  __shared__ float xs4[256][4];
  __shared__ float4 part[4][256];

  const float AA[6][5] = {
      {0.f, 0.f, 0.f, 0.f, 0.f},
      {0.2f, 0.f, 0.f, 0.f, 0.f},
      {3.f / 40.f, 9.f / 40.f, 0.f, 0.f, 0.f},
      {44.f / 45.f, -56.f / 15.f, 32.f / 9.f, 0.f, 0.f},
      {19372.f / 6561.f, -25360.f / 2187.f, 64448.f / 6561.f, -212.f / 729.f, 0.f},
      {9017.f / 3168.f, -355.f / 33.f, 46732.f / 5247.f, 49.f / 176.f, -5103.f / 18656.f}};
  const float BB[6] = {35.f / 384.f, 0.f, 500.f / 1113.f, 125.f / 192.f, -2187.f / 6784.f, 11.f / 84.f};
  const float sv[6] = {0.f, 0.2f, 0.3f, 0.8f, 8.f / 9.f, 1.f};
  float Hm[6][4];
#pragma unroll
  for (int s = 0; s < 6; s++) {
    float ss = sv[s], s2 = ss * ss, s3 = s2 * ss;
    Hm[s][0] = 2.f * s3 - 3.f * s2 + 1.f;
    Hm[s][1] = s3 - 2.f * s2 + ss;
    Hm[s][2] = -2.f * s3 + 3.f * s2;
    Hm[s][3] = s3 - s2;
  }

  // owned-column metadata
  int isF, tt;
  float brow, xc;
  if (col < 256) {
    isF = 0; tt = 0; brow = 0.f;
    xc = (i == col) ? 1.f : 0.f;
  } else {
    isF = 1; xc = 0.f;
    int f = col - 256;
    tt = f >> 5;
    brow = Bm[i * 32 + (f & 31)];
  }
  float bh[6];
#pragma unroll
  for (int s = 0; s < 6; s++) {
    float hv = (tt == 0) ? Hm[s][0] : ((tt == 1) ? Hm[s][1] : ((tt == 2) ? Hm[s][2] : Hm[s][3]));
    bh[s] = isF ? hv * brow : 0.f;
  }

  float kreg[6];
#pragma unroll
  for (int s = 0; s < 6; s++) kreg[s] = 0.f;

  int j0 = jg * 64;
#pragma unroll 1
  for (int s = 0; s < 6; s++) {
    // stage input for the owned column (register k's -> LDS)
    float xsv = xc;
#pragma unroll
    for (int j = 0; j < 5; j++)
      if (j < s) xsv += AA[s][j] * kreg[j];
    xs4[i][cc] = xsv;
    __syncthreads();
    // partial matvec over this thread's 64-row j-slice (4 cols per load)
    float acx = 0.f, acy = 0.f, acz = 0.f, acw = 0.f;
#pragma unroll 8
    for (int jj = 0; jj < 64; jj++) {
      int j = j0 + jj;
      float a = AT[(size_t)j * 256 + i];
      float4 xv = *(const float4*)xs4[j];
      acx += a * xv.x;
      acy += a * xv.y;
      acz += a * xv.z;
      acw += a * xv.w;
    }
    part[jg][i] = make_float4(acx, acy, acz, acw);
    __syncthreads();
    // owner reduces the 4 partials for its column
    float k = bh[s];
#pragma unroll
    for (int g = 0; g < 4; g++) {
      const float* p = (const float*)&part[g][i];
      k += p[cc];
    }
    kreg[s] = k;
  }

  float o = xc;
#pragma unroll
  for (int s = 0; s < 6; s++) o += BB[s] * kreg[s];
  if (!isF) {
    Rout[(size_t)i * 256 + col] = o;
    ushort_t h = bf16_hi(o);
    Rh[(size_t)i * 256 + col] = h;
    Rl[(size_t)i * 256 + col] = bf16_hi(o - bf16_f(h));
  } else {
    FcatT[(size_t)(col - 256) * 256 + i] = o;
  }
}

// Wtap[n][tap] = {u_n, m_n, u_{n+1}, m_{n+1}} taps; row 32767 = 0 (pad).
__global__ __launch_bounds__(128) void build_wtap(const float* __restrict__ u, float* __restrict__ Wtap) {
  int n = blockIdx.x;
  int tid = threadIdx.x;
  int t = tid >> 5, c = tid & 31;
  float val = 0.f;
  if (n < TPTS - 1) {
    if (t == 0) val = u[(size_t)n * 32 + c];
    else if (t == 2) val = u[(size_t)(n + 1) * 32 + c];
    else {
      int k = (t == 1) ? n : n + 1;
      if (k == 0) val = u[32 + c] - u[c];
      else if (k == TPTS - 1) val = u[(size_t)(TPTS - 1) * 32 + c] - u[(size_t)(TPTS - 2) * 32 + c];
      else val = 0.5f * (u[(size_t)(k + 1) * 32 + c] - u[(size_t)(k - 1) * 32 + c]);
    }
  }
  Wtap[(size_t)n * 128 + tid] = val;
}

// Top-level starts at stride 512: 64 blocks. X3[k] = x_{512k}.
// X3[k] = W[k-1] + R512 X3[k-1]; truncate after 3 terms:
//   k==0: x0
//   k==1: W0 + R512*x0                       (exact)
//   k==2: W1 + R512*(W0 + R512*x0)           (exact)
//   k>=3: W[k-1] + R512*(W[k-2] + R512*W[k-3])   (drops R^1536*X ~ 5e-7)
__global__ __launch_bounds__(256) void top_scan(const float* __restrict__ V3, const float* __restrict__ x0,
                                                const float* __restrict__ R512, float* __restrict__ X3) {
  int k = blockIdx.x, i = threadIdx.x;
  if (k == 0) { X3[i] = x0[i]; return; }
  __shared__ float va[256];
  __shared__ float inner[256];
  if (k == 1) {
    inner[i] = x0[i];
  } else {
    const float* vecA = (k == 2) ? x0 : (V3 + (size_t)(k - 3) * 256);
    va[i] = vecA[i];
    __syncthreads();
    float acc = V3[(size_t)(k - 2) * 256 + i];
    const float* rr = R512 + (size_t)i * 256;
    for (int j = 0; j < 256; j += 4) {
      float4 rv = *(const float4*)(rr + j);
      acc += rv.x * va[j] + rv.y * va[j + 1] + rv.z * va[j + 2] + rv.w * va[j + 3];
    }
    inner[i] = acc;
  }
  __syncthreads();
  float acc2 = V3[(size_t)(k - 1) * 256 + i];
  const float* rr2 = R512 + (size_t)i * 256;
  for (int j = 0; j < 256; j += 4) {
    float4 rv = *(const float4*)(rr2 + j);
    acc2 += rv.x * inner[j] + rv.y * inner[j + 1] + rv.z * inner[j + 2] + rv.w * inner[j + 3];
  }
  X3[(size_t)k * 256 + i] = acc2;
}

// y = x @ C^T + u @ D^T
__global__ __launch_bounds__(256) void y_kernel(const float* __restrict__ x, const float* __restrict__ u,
                                                const float* __restrict__ Cm, const float* __restrict__ Dm,
                                                float* __restrict__ y) {
  __shared__ float Cs[32][260];
  __shared__ float Ds[32][32];
  __shared__ float xs[8][256];
  __shared__ float us[8][32];
  int tid = threadIdx.x;
  for (int k = tid; k < 8192; k += 256) Cs[k >> 8][k & 255] = Cm[k];
  for (int k = tid; k < 1024; k += 256) Ds[k >> 5][k & 31] = Dm[k];
  int o = tid & 31, rr = tid >> 5;
  int n0 = blockIdx.x * 64;
  for (int g = 0; g < 8; g++) {
    int nb = n0 + g * 8;
    __syncthreads();
    for (int k = tid; k < 2048; k += 256)
      xs[k >> 8][k & 255] = x[(size_t)(nb + (k >> 8)) * 256 + (k & 255)];
    for (int k = tid; k < 256; k += 256)
      us[k >> 5][k & 31] = u[(size_t)(nb + (k >> 5)) * 32 + (k & 31)];
    __syncthreads();
    float acc = 0.f;
    for (int i = 0; i < 256; i += 4) {
      float4 cv = *(const float4*)&Cs[o][i];
      float4 xv = *(const float4*)&xs[rr][i];
      acc += cv.x * xv.x + cv.y * xv.y + cv.z * xv.z + cv.w * xv.w;
    }
#pragma unroll
    for (int c = 0; c < 32; c += 4) {
      float4 dv = *(const float4*)&Ds[o][c];
      float4 uv = *(const float4*)&us[rr][c];
      acc += dv.x * uv.x + dv.y * uv.y + dv.z * uv.z + dv.w * uv.w;
    }
    y[(size_t)(nb + rr) * 32 + o] = acc;
  }
}

extern "C" void kernel_launch(void* const* d_in, const int* in_sizes, int n_in,
                              void* d_out, int out_size, void* d_ws, size_t ws_size,
                              hipStream_t stream) {
  const float* u  = (const float*)d_in[1];
  const float* x0 = (const float*)d_in[2];
  const float* A  = (const float*)d_in[3];
  const float* Bm = (const float*)d_in[4];
  const float* Cm = (const float*)d_in[5];
  const float* Dm = (const float*)d_in[6];
  float* xout = (float*)d_out;                       // [32768][256]
  float* yout = xout + (size_t)TPTS * 256;           // [32768][32]

  char* wsb = (char*)d_ws;
  size_t off = 0;
  auto alloc = [&](size_t bytes) -> void* {
    void* p = (void*)(wsb + off);
    off = (off + bytes + 255) & ~(size_t)255;
    return p;
  };
  float*    Rfp    = (float*)alloc(65536 * 4);
  ushort_t* Rh     = (ushort_t*)alloc(65536 * 2);
  ushort_t* Rl     = (ushort_t*)alloc(65536 * 2);
  float*    PowFp  = (float*)alloc(65536 * 4);       // scratch fp out for R^8/R^64 (unused downstream)
  ushort_t* R8h    = (ushort_t*)alloc(65536 * 2);
  ushort_t* R8l    = (ushort_t*)alloc(65536 * 2);
  ushort_t* R64h   = (ushort_t*)alloc(65536 * 2);
  ushort_t* R64l   = (ushort_t*)alloc(65536 * 2);
  float*    R512fp = (float*)alloc(65536 * 4);
  ushort_t* R512h  = (ushort_t*)alloc(65536 * 2);
  ushort_t* R512l  = (ushort_t*)alloc(65536 * 2);
  float*    ATm    = (float*)alloc(65536 * 4);
  float*    FcatT  = (float*)alloc(128 * 256 * 4);
  float*    Wtap   = (float*)alloc((size_t)TPTS * 128 * 4);
  float*    V0     = (float*)alloc((size_t)TPTS * 256 * 4);
  float*    V1     = (float*)alloc(4096 * 256 * 4);
  float*    V2     = (float*)alloc(512 * 256 * 4);
  float*    V3     = (float*)alloc(64 * 256 * 4);
  float*    X3     = (float*)alloc(64 * 256 * 4);
  float*    X2     = (float*)alloc(512 * 256 * 4);
  float*    X1     = (float*)alloc(4096 * 256 * 4);
  (void)ws_size; (void)in_sizes; (void)n_in; (void)out_size;

  // 1. A^T, unit responses -> R (fp32 + hi/lo split) and FcatT
  transpose_at<<<dim3(16), dim3(256), 0, stream>>>(A, ATm);
  unit_resp<<<dim3(96), dim3(1024), 0, stream>>>(ATm, Bm, Rfp, Rh, Rl, FcatT);

  // 2. powers: R^8, R^64 = (R^8)^8, R^512 = (R^64)^8 (8 steps each)
  chain_mfma<0, 8><<<dim3(16), dim3(1024), 0, stream>>>(Rh, Rl, nullptr, nullptr, PowFp, R8h, R8l);
  chain_mfma<0, 8><<<dim3(16), dim3(1024), 0, stream>>>(R8h, R8l, nullptr, nullptr, PowFp, R64h, R64l);
  chain_mfma<0, 8><<<dim3(16), dim3(1024), 0, stream>>>(R64h, R64l, nullptr, nullptr, R512fp, R512h, R512l);

  // 3. Hermite taps and per-step drive v_n (fp32 GEMM, K=128)
  build_wtap<<<dim3(TPTS), dim3(128), 0, stream>>>(u, Wtap);
  gemm128<<<dim3(256, 2), dim3(256), 0, stream>>>(Wtap, FcatT, V0, TPTS, 128);

  // 4. reduces (7 steps each): V1[4096] <- V0, V2[512] <- V1, V3[64] <- V2
  chain_mfma<1, 8><<<dim3(256), dim3(1024), 0, stream>>>(Rh, Rl, nullptr, V0, V1, nullptr, nullptr);
  chain_mfma<1, 8><<<dim3(32), dim3(1024), 0, stream>>>(R8h, R8l, nullptr, V1, V2, nullptr, nullptr);
  chain_mfma<1, 8><<<dim3(4), dim3(1024), 0, stream>>>(R64h, R64l, nullptr, V2, V3, nullptr, nullptr);

  // 5. top starts (64 @ stride 512), then expand down three levels (7 steps each)
  top_scan<<<dim3(64), dim3(256), 0, stream>>>(V3, x0, R512fp, X3);
  chain_mfma<2, 8><<<dim3(4), dim3(1024), 0, stream>>>(R64h, R64l, X3, V2, X2, nullptr, nullptr);
  chain_mfma<2, 8><<<dim3(32), dim3(1024), 0, stream>>>(R8h, R8l, X2, V1, X1, nullptr, nullptr);
  chain_mfma<2, 8><<<dim3(256), dim3(1024), 0, stream>>>(Rh, Rl, X1, V0, xout, nullptr, nullptr);

  // 6. outputs y
  y_kernel<<<dim3(512), dim3(256), 0, stream>>>(xout, u, Cm, Dm, yout);
}

// Round 6
// 342.311 us; speedup vs baseline: 1.5252x; 1.0614x over previous
//
#include <hip/hip_runtime.h>

// Flow_49160195670664: Dopri5 fixed-step integration of dx/dt = A x + B u(t),
// T=32768, N=256, NI=NO=32, dt=1, Hermite-interpolated stage inputs.
// Linear system => x_{n+1} = R x_n + v_n with constant R.
// v4: 4-level blocked parallel scan 8 x 8 x 8 x 64 (was 32x32x32).
// Rationale (r3 counters): per-step time of chain_mfma is ~1.75us regardless
// of block count (64-blk and 2-blk dispatches both ~54us) -> sequential-step
// latency floor. 3-level tree paid 188 steps (~324us); 4-level pays 66 steps
// (powers 8+8+8, reduces 7+7+7, expands 7+7+7) and puts 256 blocks on the
// finest level. Top level: 64 starts with R^512, 3-term truncated recurrence
// (error ~||R^1536|| ~ 5e-7; exact for k<=2).
// v5: y_kernel register-tiled 4x4 (r5 counters: old y was LDS-throughput-bound,
// 4 FLOP/ds_read, 3.67M bank-conflict cycles, 46us).

#define TPTS 32768

typedef __attribute__((ext_vector_type(8))) short short8;
typedef __attribute__((ext_vector_type(4))) float float4v;
typedef unsigned short ushort_t;

__device__ __forceinline__ ushort_t bf16_hi(float f) {
  unsigned u = __builtin_bit_cast(unsigned, f);
  unsigned r = (u + 0x7FFFu + ((u >> 16) & 1u)) >> 16;
  return (ushort_t)r;
}
__device__ __forceinline__ float bf16_f(ushort_t h) {
  unsigned u = ((unsigned)h) << 16;
  return __builtin_bit_cast(float, u);
}

// ---------------------------------------------------------------------------
// MFMA chain kernel v4. 1024 thr = 16 waves; wave w owns output cols
// [16w,16w+16) as ONE N-tile of mfma_f32_16x16x32_bf16; 16 chains = M-dim.
// bf16 hi/lo split (x*R ~ xh*Rh + xl*Rh + xh*Rl, fp32 accumulate), 3
// independent accumulators. V-drive register-prefetched one step ahead.
// CLEN = rows per chain (8 for scan levels). STEPS = CLEN (MODE 0) or CLEN-1.
// MODE 0: power  (CLEN steps, x0 = I cols; Out = M^CLEN row-major fp32 + h/l)
// MODE 1: reduce (x0 = V row0 of chain, drive rows 1..CLEN-1; Out[chain]=final)
// MODE 2: expand (x0 = X0[chain], drive rows 0..CLEN-2; Out rows chain*CLEN+j)
// MODE 2 stores go through a 5-slot LDS ring: rows 1..4(+) flushed in groups
// of 4 right after a barrier; final 3 rows (STEPS-2..STEPS) at the end.
template <int MODE, int CLEN>
__global__ __launch_bounds__(1024, 4) void chain_mfma(const ushort_t* Mh, const ushort_t* Ml,
                                                      const float* X0, const float* V,
                                                      float* Out, ushort_t* OutH, ushort_t* OutL) {
  constexpr int STEPS = (MODE == 0) ? CLEN : CLEN - 1;
  constexpr int HSLOTS = (MODE == 2) ? 5 : 1;
  int blk = blockIdx.x, t = threadIdx.x;
  int w = t >> 6, l = t & 63;   // w 0..15
  int q = l >> 4, c16 = l & 15;
  int n0 = w * 16;
  // B-frags: B[k][n] = M[n][k]; lane holds B[kt*32+q*8+j][n0+c16], j=0..7
  short8 bh[8], bl[8];
#pragma unroll
  for (int kt = 0; kt < 8; kt++) {
    size_t offs = (size_t)(n0 + c16) * 256 + kt * 32 + q * 8;
    bh[kt] = *(const short8*)(Mh + offs);
    bl[kt] = *(const short8*)(Ml + offs);
  }
  __shared__ __attribute__((aligned(16))) ushort_t xh[2][32][16][8];  // [buf][k>>3][chain][k&7]
  __shared__ __attribute__((aligned(16))) ushort_t xl[2][32][16][8];
  __shared__ float hist[HSLOTS][16][256];
  // initial x (and row-0 store for MODE 2): 1024 float4, one per thread
  {
    int e = t;
    int c = e >> 6, qq = (e & 63) * 4;
    int cg = blk * 16 + c;
    float4 v4;
    if (MODE == 0) {
      v4 = make_float4(qq == cg ? 1.f : 0.f, qq + 1 == cg ? 1.f : 0.f,
                       qq + 2 == cg ? 1.f : 0.f, qq + 3 == cg ? 1.f : 0.f);
    } else if (MODE == 1) {
      v4 = *(const float4*)(V + (size_t)cg * CLEN * 256 + qq);
    } else {
      v4 = *(const float4*)(X0 + (size_t)cg * 256 + qq);
      *(float4*)(Out + ((size_t)cg * CLEN) * 256 + qq) = v4;
    }
    float vals[4] = {v4.x, v4.y, v4.z, v4.w};
#pragma unroll
    for (int i = 0; i < 4; i++) {
      int n = qq + i;
      ushort_t h = bf16_hi(vals[i]);
      xh[0][n >> 3][c][n & 7] = h;
      xl[0][n >> 3][c][n & 7] = bf16_hi(vals[i] - bf16_f(h));
    }
  }
  // per-lane drive prefetch for step 1 (element r: chain q*4+r, col n0+c16)
  float vnext[4];
  if (MODE != 0) {
#pragma unroll
    for (int r = 0; r < 4; r++) {
      int cg = blk * 16 + q * 4 + r;
      int drow = (MODE == 1) ? 1 : 0;
      vnext[r] = V[((size_t)cg * CLEN + drow) * 256 + n0 + c16];
    }
  }
  __syncthreads();
  for (int s = 1; s <= STEPS; s++) {
    int cur = (s - 1) & 1, nxt = s & 1;
    // MODE 2: flush rows s-4..s-1 (slots row%5) — reads race-free vs writes (mod-5 disjoint)
    if (MODE == 2 && s >= 5 && ((s - 1) & 3) == 0) {
      int rbase = s - 4;
      for (int e = t; e < 4096; e += 1024) {
        int slot = e >> 10;
        int rem = e & 1023;
        int c = rem >> 6, qq = (rem & 63) * 4;
        int row = rbase + slot;
        int cg = blk * 16 + c;
        *(float4*)(Out + ((size_t)cg * CLEN + row) * 256 + qq) = *(const float4*)&hist[row % 5][c][qq];
      }
    }
    // drive: consume prefetched, issue next step's loads (hidden under MFMAs)
    float vc[4];
    if (MODE != 0) {
#pragma unroll
      for (int i2 = 0; i2 < 4; i2++) vc[i2] = vnext[i2];
      if (s < STEPS) {
        int drow = (MODE == 1) ? (s + 1) : s;
#pragma unroll
        for (int r = 0; r < 4; r++)
          vnext[r] = V[((size_t)(blk * 16 + q * 4 + r) * CLEN + drow) * 256 + n0 + c16];
      }
    }
    // pin frags: rw asm operand => value must live in VGPRs, reload illegal
#pragma unroll
    for (int kt = 0; kt < 8; kt++) {
      asm volatile("" : "+v"(bh[kt]));
      asm volatile("" : "+v"(bl[kt]));
    }
    float4v aH = {0.f, 0.f, 0.f, 0.f};
    float4v aL = {0.f, 0.f, 0.f, 0.f};
    float4v aC = {0.f, 0.f, 0.f, 0.f};
#pragma unroll
    for (int kt = 0; kt < 8; kt++) {
      short8 ah = *(const short8*)&xh[cur][kt * 4 + q][c16][0];
      short8 al = *(const short8*)&xl[cur][kt * 4 + q][c16][0];
      aH = __builtin_amdgcn_mfma_f32_16x16x32_bf16(ah, bh[kt], aH, 0, 0, 0);
      aL = __builtin_amdgcn_mfma_f32_16x16x32_bf16(al, bh[kt], aL, 0, 0, 0);
      aC = __builtin_amdgcn_mfma_f32_16x16x32_bf16(ah, bl[kt], aC, 0, 0, 0);
    }
    // epilogue: C/D layout chain=(q*4+r), col=c16 (m89-verified)
#pragma unroll
    for (int r = 0; r < 4; r++) {
      int c = q * 4 + r;
      int n = n0 + c16;
      float val = aH[r] + aL[r] + aC[r];
      if (MODE != 0) val += vc[r];
      int cg = blk * 16 + c;
      if (MODE == 2) hist[s % 5][c][n] = val;
      if (MODE == 1 && s == STEPS) Out[(size_t)cg * 256 + n] = val;
      if (MODE == 0 && s == STEPS) {
        ushort_t h2 = bf16_hi(val);
        Out[(size_t)n * 256 + cg] = val;
        OutH[(size_t)n * 256 + cg] = h2;
        OutL[(size_t)n * 256 + cg] = bf16_hi(val - bf16_f(h2));
      }
      ushort_t h = bf16_hi(val);
      xh[nxt][n >> 3][c][n & 7] = h;
      xl[nxt][n >> 3][c][n & 7] = bf16_hi(val - bf16_f(h));
    }
    __syncthreads();
  }
  if (MODE == 2) {   // final rows STEPS-2..STEPS
    for (int e = t; e < 3072; e += 1024) {
      int slot = e >> 10;
      int rem = e & 1023;
      int c = rem >> 6, qq = (rem & 63) * 4;
      int row = (STEPS - 2) + slot;
      int cg = blk * 16 + c;
      *(float4*)(Out + ((size_t)cg * CLEN + row) * 256 + qq) = *(const float4*)&hist[row % 5][c][qq];
    }
  }
}

// ---------------------------------------------------------------------------
// fp32 GEMM for the drive: C[M][256] = A[M][K] @ B[K][256], BM=BN=128, BK=8.
__global__ __launch_bounds__(256) void gemm128(const float* __restrict__ A, const float* __restrict__ B,
                                               float* __restrict__ C, int M, int K) {
  int m0 = blockIdx.x * 128, n0 = blockIdx.y * 128;
  __shared__ float As[8][128];
  __shared__ float Bs[8][128];
  int tid = threadIdx.x;
  int am = tid >> 1, akc = (tid & 1) * 4;
  int bk = tid >> 5, bn = (tid & 31) * 4;
  int ty = tid >> 4, tx = tid & 15;
  float acc[8][8] = {{0.f}};
  for (int kt = 0; kt < K; kt += 8) {
    float4 av = make_float4(0.f, 0.f, 0.f, 0.f);
    if (m0 + am < M) av = *(const float4*)(A + (size_t)(m0 + am) * K + kt + akc);
    float4 bv = *(const float4*)(B + (size_t)(kt + bk) * 256 + n0 + bn);
    __syncthreads();
    As[akc + 0][am] = av.x;
    As[akc + 1][am] = av.y;
    As[akc + 2][am] = av.z;
    As[akc + 3][am] = av.w;
    *(float4*)&Bs[bk][bn] = bv;
    __syncthreads();
#pragma unroll
    for (int kk = 0; kk < 8; kk++) {
      float4 a0 = *(const float4*)&As[kk][ty * 8];
      float4 a1 = *(const float4*)&As[kk][ty * 8 + 4];
      float4 b0 = *(const float4*)&Bs[kk][tx * 8];
      float4 b1 = *(const float4*)&Bs[kk][tx * 8 + 4];
      float ar[8] = {a0.x, a0.y, a0.z, a0.w, a1.x, a1.y, a1.z, a1.w};
      float br[8] = {b0.x, b0.y, b0.z, b0.w, b1.x, b1.y, b1.z, b1.w};
#pragma unroll
      for (int i = 0; i < 8; i++)
#pragma unroll
        for (int j = 0; j < 8; j++) acc[i][j] += ar[i] * br[j];
    }
  }
#pragma unroll
  for (int i = 0; i < 8; i++) {
    int row = m0 + ty * 8 + i;
    if (row < M) {
      *(float4*)&C[(size_t)row * 256 + n0 + tx * 8] = make_float4(acc[i][0], acc[i][1], acc[i][2], acc[i][3]);
      *(float4*)&C[(size_t)row * 256 + n0 + tx * 8 + 4] = make_float4(acc[i][4], acc[i][5], acc[i][6], acc[i][7]);
    }
  }
}

// AT = A^T (256x256)
__global__ __launch_bounds__(256) void transpose_at(const float* __restrict__ A, float* __restrict__ AT) {
  __shared__ float tile[64][65];
  int bx = blockIdx.x & 3, by = blockIdx.x >> 2;
  int r0 = by * 64, c0 = bx * 64;
  int t = threadIdx.x;
  int lr = t >> 4, lc = (t & 15) * 4;
  for (int rr = lr; rr < 64; rr += 16) {
    float4 v = *(const float4*)(A + (size_t)(r0 + rr) * 256 + c0 + lc);
    tile[rr][lc + 0] = v.x; tile[rr][lc + 1] = v.y; tile[rr][lc + 2] = v.z; tile[rr][lc + 3] = v.w;
  }
  __syncthreads();
  for (int rr = lr; rr < 64; rr += 16) {
    float4 v = make_float4(tile[lc + 0][rr], tile[lc + 1][rr], tile[lc + 2][rr], tile[lc + 3][rr]);
    *(float4*)(AT + (size_t)(c0 + rr) * 256 + r0 + lc) = v;
  }
}

// Unit responses through one Dopri5 step: cols 0..255 -> R fp32 + bf16 hi/lo
// split; cols 256..383 -> Hermite-folded tap matrices transposed into FcatT.
// v2: 1024 threads = 4 j-groups x 256 rows; 4-way split-K with LDS reduce.
__global__ __launch_bounds__(1024) void unit_resp(const float* __restrict__ AT,
                                                  const float* __restrict__ Bm,
                                                  float* __restrict__ Rout,
                                                  ushort_t* __restrict__ Rh,
                                                  ushort_t* __restrict__ Rl,
                                                  float* __restrict__ FcatT) {
  int blk = blockIdx.x;
  int tid = threadIdx.x;
  int jg = tid >> 8;   // j-group 0..3, also the owned column index cc
  int i = tid & 255;   // output row
  int cc = jg;
  int col = blk * 4 + cc;

  __shared__ float xs4[256][4];
  __shared__ float4 part[4][256];

  const float AA[6][5] = {
      {0.f, 0.f, 0.f, 0.f, 0.f},
      {0.2f, 0.f, 0.f, 0.f, 0.f},
      {3.f / 40.f, 9.f / 40.f, 0.f, 0.f, 0.f},
      {44.f / 45.f, -56.f / 15.f, 32.f / 9.f, 0.f, 0.f},
      {19372.f / 6561.f, -25360.f / 2187.f, 64448.f / 6561.f, -212.f / 729.f, 0.f},
      {9017.f / 3168.f, -355.f / 33.f, 46732.f / 5247.f, 49.f / 176.f, -5103.f / 18656.f}};
  const float BB[6] = {35.f / 384.f, 0.f, 500.f / 1113.f, 125.f / 192.f, -2187.f / 6784.f, 11.f / 84.f};
  const float sv[6] = {0.f, 0.2f, 0.3f, 0.8f, 8.f / 9.f, 1.f};
  float Hm[6][4];
#pragma unroll
  for (int s = 0; s < 6; s++) {
    float ss = sv[s], s2 = ss * ss, s3 = s2 * ss;
    Hm[s][0] = 2.f * s3 - 3.f * s2 + 1.f;
    Hm[s][1] = s3 - 2.f * s2 + ss;
    Hm[s][2] = -2.f * s3 + 3.f * s2;
    Hm[s][3] = s3 - s2;
  }

  // owned-column metadata
  int isF, tt;
  float brow, xc;
  if (col < 256) {
    isF = 0; tt = 0; brow = 0.f;
    xc = (i == col) ? 1.f : 0.f;
  } else {
    isF = 1; xc = 0.f;
    int f = col - 256;
    tt = f >> 5;
    brow = Bm[i * 32 + (f & 31)];
  }
  float bh[6];
#pragma unroll
  for (int s = 0; s < 6; s++) {
    float hv = (tt == 0) ? Hm[s][0] : ((tt == 1) ? Hm[s][1] : ((tt == 2) ? Hm[s][2] : Hm[s][3]));
    bh[s] = isF ? hv * brow : 0.f;
  }

  float kreg[6];
#pragma unroll
  for (int s = 0; s < 6; s++) kreg[s] = 0.f;

  int j0 = jg * 64;
#pragma unroll 1
  for (int s = 0; s < 6; s++) {
    // stage input for the owned column (register k's -> LDS)
    float xsv = xc;
#pragma unroll
    for (int j = 0; j < 5; j++)
      if (j < s) xsv += AA[s][j] * kreg[j];
    xs4[i][cc] = xsv;
    __syncthreads();
    // partial matvec over this thread's 64-row j-slice (4 cols per load)
    float acx = 0.f, acy = 0.f, acz = 0.f, acw = 0.f;
#pragma unroll 8
    for (int jj = 0; jj < 64; jj++) {
      int j = j0 + jj;
      float a = AT[(size_t)j * 256 + i];
      float4 xv = *(const float4*)xs4[j];
      acx += a * xv.x;
      acy += a * xv.y;
      acz += a * xv.z;
      acw += a * xv.w;
    }
    part[jg][i] = make_float4(acx, acy, acz, acw);
    __syncthreads();
    // owner reduces the 4 partials for its column
    float k = bh[s];
#pragma unroll
    for (int g = 0; g < 4; g++) {
      const float* p = (const float*)&part[g][i];
      k += p[cc];
    }
    kreg[s] = k;
  }

  float o = xc;
#pragma unroll
  for (int s = 0; s < 6; s++) o += BB[s] * kreg[s];
  if (!isF) {
    Rout[(size_t)i * 256 + col] = o;
    ushort_t h = bf16_hi(o);
    Rh[(size_t)i * 256 + col] = h;
    Rl[(size_t)i * 256 + col] = bf16_hi(o - bf16_f(h));
  } else {
    FcatT[(size_t)(col - 256) * 256 + i] = o;
  }
}

// Wtap[n][tap] = {u_n, m_n, u_{n+1}, m_{n+1}} taps; row 32767 = 0 (pad).
__global__ __launch_bounds__(128) void build_wtap(const float* __restrict__ u, float* __restrict__ Wtap) {
  int n = blockIdx.x;
  int tid = threadIdx.x;
  int t = tid >> 5, c = tid & 31;
  float val = 0.f;
  if (n < TPTS - 1) {
    if (t == 0) val = u[(size_t)n * 32 + c];
    else if (t == 2) val = u[(size_t)(n + 1) * 32 + c];
    else {
      int k = (t == 1) ? n : n + 1;
      if (k == 0) val = u[32 + c] - u[c];
      else if (k == TPTS - 1) val = u[(size_t)(TPTS - 1) * 32 + c] - u[(size_t)(TPTS - 2) * 32 + c];
      else val = 0.5f * (u[(size_t)(k + 1) * 32 + c] - u[(size_t)(k - 1) * 32 + c]);
    }
  }
  Wtap[(size_t)n * 128 + tid] = val;
}

// Top-level starts at stride 512: 64 blocks. X3[k] = x_{512k}.
// X3[k] = W[k-1] + R512 X3[k-1]; truncate after 3 terms:
//   k==0: x0
//   k==1: W0 + R512*x0                       (exact)
//   k==2: W1 + R512*(W0 + R512*x0)           (exact)
//   k>=3: W[k-1] + R512*(W[k-2] + R512*W[k-3])   (drops R^1536*X ~ 5e-7)
__global__ __launch_bounds__(256) void top_scan(const float* __restrict__ V3, const float* __restrict__ x0,
                                                const float* __restrict__ R512, float* __restrict__ X3) {
  int k = blockIdx.x, i = threadIdx.x;
  if (k == 0) { X3[i] = x0[i]; return; }
  __shared__ float va[256];
  __shared__ float inner[256];
  if (k == 1) {
    inner[i] = x0[i];
  } else {
    const float* vecA = (k == 2) ? x0 : (V3 + (size_t)(k - 3) * 256);
    va[i] = vecA[i];
    __syncthreads();
    float acc = V3[(size_t)(k - 2) * 256 + i];
    const float* rr = R512 + (size_t)i * 256;
    for (int j = 0; j < 256; j += 4) {
      float4 rv = *(const float4*)(rr + j);
      acc += rv.x * va[j] + rv.y * va[j + 1] + rv.z * va[j + 2] + rv.w * va[j + 3];
    }
    inner[i] = acc;
  }
  __syncthreads();
  float acc2 = V3[(size_t)(k - 1) * 256 + i];
  const float* rr2 = R512 + (size_t)i * 256;
  for (int j = 0; j < 256; j += 4) {
    float4 rv = *(const float4*)(rr2 + j);
    acc2 += rv.x * inner[j] + rv.y * inner[j + 1] + rv.z * inner[j + 2] + rv.w * inner[j + 3];
  }
  X3[(size_t)k * 256 + i] = acc2;
}

// y = x @ C^T + u @ D^T. v3: register-tiled 4x4.
// 256 blocks x 256 thr; block owns 128 rows. Thread (rt=tid>>3, ct=tid&7)
// computes rows n0+rt*4+0..3 x cols ct*4+0..3. C/D stored TRANSPOSED in LDS
// (CsT[i][o], [256][36] pad): per-i read CsT[i][4ct..4ct+3] is 8 consecutive
// 16B chunks across the wave = all 32 banks once -> conflict-free (row-major
// Cs with 16B-aligned rows provably can't be). x read straight from global
// (L3-resident; 8 ct-lanes share addresses -> collapses); zero x staging.
// 32 FLOP per LDS read vs 4 in v2 (which was LDS-throughput-bound at 46us).
__global__ __launch_bounds__(256) void y_kernel(const float* __restrict__ x, const float* __restrict__ u,
                                                const float* __restrict__ Cm, const float* __restrict__ Dm,
                                                float* __restrict__ y) {
  __shared__ float CsT[256][36];
  __shared__ float DsT[32][36];
  int tid = threadIdx.x;
  for (int k = tid; k < 8192; k += 256) CsT[k & 255][k >> 8] = Cm[k];
  for (int k = tid; k < 1024; k += 256) DsT[k & 31][k >> 5] = Dm[k];
  __syncthreads();
  int rt = tid >> 3, ct = tid & 7;
  int n0 = blockIdx.x * 128 + rt * 4;
  int o0 = ct * 4;
  float acc[4][4] = {{0.f}};
#pragma unroll 4
  for (int i = 0; i < 256; i += 4) {
    float4 cv0 = *(const float4*)&CsT[i + 0][o0];
    float4 cv1 = *(const float4*)&CsT[i + 1][o0];
    float4 cv2 = *(const float4*)&CsT[i + 2][o0];
    float4 cv3 = *(const float4*)&CsT[i + 3][o0];
#pragma unroll
    for (int r = 0; r < 4; r++) {
      float4 xv = *(const float4*)(x + (size_t)(n0 + r) * 256 + i);
      acc[r][0] += xv.x * cv0.x + xv.y * cv1.x + xv.z * cv2.x + xv.w * cv3.x;
      acc[r][1] += xv.x * cv0.y + xv.y * cv1.y + xv.z * cv2.y + xv.w * cv3.y;
      acc[r][2] += xv.x * cv0.z + xv.y * cv1.z + xv.z * cv2.z + xv.w * cv3.z;
      acc[r][3] += xv.x * cv0.w + xv.y * cv1.w + xv.z * cv2.w + xv.w * cv3.w;
    }
  }
#pragma unroll
  for (int i = 0; i < 32; i += 4) {
    float4 dv0 = *(const float4*)&DsT[i + 0][o0];
    float4 dv1 = *(const float4*)&DsT[i + 1][o0];
    float4 dv2 = *(const float4*)&DsT[i + 2][o0];
    float4 dv3 = *(const float4*)&DsT[i + 3][o0];
#pragma unroll
    for (int r = 0; r < 4; r++) {
      float4 uv = *(const float4*)(u + (size_t)(n0 + r) * 32 + i);
      acc[r][0] += uv.x * dv0.x + uv.y * dv1.x + uv.z * dv2.x + uv.w * dv3.x;
      acc[r][1] += uv.x * dv0.y + uv.y * dv1.y + uv.z * dv2.y + uv.w * dv3.y;
      acc[r][2] += uv.x * dv0.z + uv.y * dv1.z + uv.z * dv2.z + uv.w * dv3.z;
      acc[r][3] += uv.x * dv0.w + uv.y * dv1.w + uv.z * dv2.w + uv.w * dv3.w;
    }
  }
#pragma unroll
  for (int r = 0; r < 4; r++)
    *(float4*)(y + (size_t)(n0 + r) * 32 + o0) =
        make_float4(acc[r][0], acc[r][1], acc[r][2], acc[r][3]);
}

extern "C" void kernel_launch(void* const* d_in, const int* in_sizes, int n_in,
                              void* d_out, int out_size, void* d_ws, size_t ws_size,
                              hipStream_t stream) {
  const float* u  = (const float*)d_in[1];
  const float* x0 = (const float*)d_in[2];
  const float* A  = (const float*)d_in[3];
  const float* Bm = (const float*)d_in[4];
  const float* Cm = (const float*)d_in[5];
  const float* Dm = (const float*)d_in[6];
  float* xout = (float*)d_out;                       // [32768][256]
  float* yout = xout + (size_t)TPTS * 256;           // [32768][32]

  char* wsb = (char*)d_ws;
  size_t off = 0;
  auto alloc = [&](size_t bytes) -> void* {
    void* p = (void*)(wsb + off);
    off = (off + bytes + 255) & ~(size_t)255;
    return p;
  };
  float*    Rfp    = (float*)alloc(65536 * 4);
  ushort_t* Rh     = (ushort_t*)alloc(65536 * 2);
  ushort_t* Rl     = (ushort_t*)alloc(65536 * 2);
  float*    PowFp  = (float*)alloc(65536 * 4);       // scratch fp out for R^8/R^64 (unused downstream)
  ushort_t* R8h    = (ushort_t*)alloc(65536 * 2);
  ushort_t* R8l    = (ushort_t*)alloc(65536 * 2);
  ushort_t* R64h   = (ushort_t*)alloc(65536 * 2);
  ushort_t* R64l   = (ushort_t*)alloc(65536 * 2);
  float*    R512fp = (float*)alloc(65536 * 4);
  ushort_t* R512h  = (ushort_t*)alloc(65536 * 2);
  ushort_t* R512l  = (ushort_t*)alloc(65536 * 2);
  float*    ATm    = (float*)alloc(65536 * 4);
  float*    FcatT  = (float*)alloc(128 * 256 * 4);
  float*    Wtap   = (float*)alloc((size_t)TPTS * 128 * 4);
  float*    V0     = (float*)alloc((size_t)TPTS * 256 * 4);
  float*    V1     = (float*)alloc(4096 * 256 * 4);
  float*    V2     = (float*)alloc(512 * 256 * 4);
  float*    V3     = (float*)alloc(64 * 256 * 4);
  float*    X3     = (float*)alloc(64 * 256 * 4);
  float*    X2     = (float*)alloc(512 * 256 * 4);
  float*    X1     = (float*)alloc(4096 * 256 * 4);
  (void)ws_size; (void)in_sizes; (void)n_in; (void)out_size;

  // 1. A^T, unit responses -> R (fp32 + hi/lo split) and FcatT
  transpose_at<<<dim3(16), dim3(256), 0, stream>>>(A, ATm);
  unit_resp<<<dim3(96), dim3(1024), 0, stream>>>(ATm, Bm, Rfp, Rh, Rl, FcatT);

  // 2. powers: R^8, R^64 = (R^8)^8, R^512 = (R^64)^8 (8 steps each)
  chain_mfma<0, 8><<<dim3(16), dim3(1024), 0, stream>>>(Rh, Rl, nullptr, nullptr, PowFp, R8h, R8l);
  chain_mfma<0, 8><<<dim3(16), dim3(1024), 0, stream>>>(R8h, R8l, nullptr, nullptr, PowFp, R64h, R64l);
  chain_mfma<0, 8><<<dim3(16), dim3(1024), 0, stream>>>(R64h, R64l, nullptr, nullptr, R512fp, R512h, R512l);

  // 3. Hermite taps and per-step drive v_n (fp32 GEMM, K=128)
  build_wtap<<<dim3(TPTS), dim3(128), 0, stream>>>(u, Wtap);
  gemm128<<<dim3(256, 2), dim3(256), 0, stream>>>(Wtap, FcatT, V0, TPTS, 128);

  // 4. reduces (7 steps each): V1[4096] <- V0, V2[512] <- V1, V3[64] <- V2
  chain_mfma<1, 8><<<dim3(256), dim3(1024), 0, stream>>>(Rh, Rl, nullptr, V0, V1, nullptr, nullptr);
  chain_mfma<1, 8><<<dim3(32), dim3(1024), 0, stream>>>(R8h, R8l, nullptr, V1, V2, nullptr, nullptr);
  chain_mfma<1, 8><<<dim3(4), dim3(1024), 0, stream>>>(R64h, R64l, nullptr, V2, V3, nullptr, nullptr);

  // 5. top starts (64 @ stride 512), then expand down three levels (7 steps each)
  top_scan<<<dim3(64), dim3(256), 0, stream>>>(V3, x0, R512fp, X3);
  chain_mfma<2, 8><<<dim3(4), dim3(1024), 0, stream>>>(R64h, R64l, X3, V2, X2, nullptr, nullptr);
  chain_mfma<2, 8><<<dim3(32), dim3(1024), 0, stream>>>(R8h, R8l, X2, V1, X1, nullptr, nullptr);
  chain_mfma<2, 8><<<dim3(256), dim3(1024), 0, stream>>>(Rh, Rl, X1, V0, xout, nullptr, nullptr);

  // 6. outputs y
  y_kernel<<<dim3(256), dim3(256), 0, stream>>>(xout, u, Cm, Dm, yout);
}